// Round 6
// baseline (847.552 us; speedup 1.0000x reference)
//
#include <hip/hip_runtime.h>
#include <hip/hip_bf16.h>

// MoEFSCIL: B=16, H=W=16, L=256, DIM=768, NH=8, HD=96, NEXP=8, TOPK=2.
// fp32 in/out. ALL GEMMs (incl. attention) bf16 MFMA; scan = fused segmented
// TWO-PASS recompute (8seg x 32step, r3 structure) with PRE-PERMUTED dblm2:
// mk_dbl writes per-dir traversal order w/ bank-staggered ss=(s&31)*8+seg, so
// scan's per-step LDS reads are base+imm (ZERO addr VALU, conflict-free).
// r5 lesson: scan was VALU-bound on swizzle/address arithmetic (~30/step),
// not chain latency. Spill law: no >=32-float per-thread saved state.

#define LTOK 256
#define DIMC 768

typedef unsigned short ushortt;
typedef __attribute__((ext_vector_type(8))) short bf16x8;
typedef __attribute__((ext_vector_type(4))) float f32x4;

#define LOG2E 1.44269504f
#define LN2   0.69314718f

__device__ __forceinline__ float fexp2(float x) { return __builtin_amdgcn_exp2f(x); }
__device__ __forceinline__ float flog2(float x) { return __builtin_amdgcn_logf(x); }

__device__ __forceinline__ ushortt f2b(float f) {
  union { float f; unsigned u; } c; c.f = f;
  unsigned r = (c.u + 0x7FFFu + ((c.u >> 16) & 1u)) >> 16;
  return (ushortt)r;
}

// ---------------------------------------------------------------------------
// Fused 4-tensor fp32->bf16 cast (x, sa_in_w, sa_out_w, ca_in_w[:768] rows).
// ---------------------------------------------------------------------------
__global__ __launch_bounds__(256) void mk_mcast4(
    const float* __restrict__ s0, ushortt* __restrict__ d0,
    const float* __restrict__ s1, ushortt* __restrict__ d1,
    const float* __restrict__ s2, ushortt* __restrict__ d2,
    const float* __restrict__ s3, ushortt* __restrict__ d3)
{
  long g = (long)blockIdx.x * 256 + threadIdx.x;   // float4 chunk id
  const float* s; ushortt* dst; long o;
  if (g < 786432)       { s = s0; dst = d0; o = g; }
  else if (g < 1228800) { s = s1; dst = d1; o = g - 786432; }
  else if (g < 1376256) { s = s2; dst = d2; o = g - 1228800; }
  else                  { s = s3; dst = d3; o = g - 1376256; }
  o <<= 2;
  float4 v = *(const float4*)(s + o);
  ushort4 w;
  w.x = f2b(v.x); w.y = f2b(v.y); w.z = f2b(v.z); w.w = f2b(v.w);
  *(ushort4*)(dst + o) = w;
}

__global__ __launch_bounds__(256) void mk_cast(const float* __restrict__ in,
                                               ushortt* __restrict__ outp, long n)
{
  long i = ((long)blockIdx.x * 256 + threadIdx.x) * 4;
  if (i + 3 < n) {
    float4 v = *(const float4*)(in + i);
    ushort4 o;
    o.x = f2b(v.x); o.y = f2b(v.y); o.z = f2b(v.z); o.w = f2b(v.w);
    *(ushort4*)(outp + i) = o;
  }
}

// ---------------------------------------------------------------------------
// bf16 MFMA GEMM: C[z] = A[z](M,K) @ B[z](N,K)^T + bias.
// Batch: pairExp (MoE) or zdiv (z1=z/zdiv, z2=z%zdiv) offsets.
// Column split at splitN: cols<splitN -> C (outBf), else C2 (outBf2, ldc2).
// c2vt: C2 written in vt layout [(b*8+h)*128 + j][t], b=row>>8, t=row&255,
//       h=(col-splitN)/96, j=(col-splitN)%96 (for the qkv v-transpose).
// ---------------------------------------------------------------------------
__global__ __launch_bounds__(256) void mk_mfma(
    const ushortt* __restrict__ A, const ushortt* __restrict__ B,
    const float* __restrict__ bias, void* __restrict__ C,
    int K, int lda, int ldb, int ldc,
    int zdiv, long sA1, long sA2, long sB1, long sB2, long sC1, long sC2,
    long sBias,
    const int* __restrict__ pairExp, int tilesN,
    int outBf, int splitN, void* __restrict__ C2, int ldc2, int outBf2, int c2vt)
{
  int z = blockIdx.y;
  long aoff, boff, coff, biasoff = 0;
  if (pairExp) {
    int e = pairExp[z];
    aoff = (long)(z >> 1) * sA1; boff = (long)e * sB1;
    coff = (long)z * sC1; biasoff = (long)e * sBias;
  } else {
    int z1 = z / zdiv, z2 = z - z1 * zdiv;
    aoff = (long)z1 * sA1 + (long)z2 * sA2;
    boff = (long)z1 * sB1 + (long)z2 * sB2;
    coff = (long)z1 * sC1 + (long)z2 * sC2;
  }
  int tile = blockIdx.x;
  int tm = tile / tilesN, tn = tile - tm * tilesN;
  long m0 = (long)tm << 7, n0 = (long)tn << 7;

  __shared__ ushortt As[128][40];
  __shared__ ushortt Bs[128][40];

  int tid = threadIdx.x;
  int lane = tid & 63, wvi = tid >> 6;
  int wr = wvi >> 1, wc = wvi & 1;
  int lm = lane & 15, lg = lane >> 4;

  f32x4 zero4 = {0.f, 0.f, 0.f, 0.f};
  f32x4 acc[4][4];
#pragma unroll
  for (int i = 0; i < 4; i++)
#pragma unroll
    for (int j = 0; j < 4; j++) acc[i][j] = zero4;

  const ushortt* Ab = A + aoff;
  const ushortt* Bb = B + boff;

  for (int k0 = 0; k0 < K; k0 += 32) {
#pragma unroll
    for (int h = 0; h < 2; h++) {
      int q = tid + h * 256;
      int row = q >> 2, ck = (q & 3) << 3;
      *(uint4*)&As[row][ck] = *(const uint4*)(Ab + (m0 + row) * lda + k0 + ck);
      *(uint4*)&Bs[row][ck] = *(const uint4*)(Bb + (n0 + row) * ldb + k0 + ck);
    }
    __syncthreads();
    bf16x8 af[4], bfr[4];
#pragma unroll
    for (int i = 0; i < 4; i++)
      af[i] = *(const bf16x8*)&As[wr * 64 + i * 16 + lm][lg << 3];
#pragma unroll
    for (int j = 0; j < 4; j++)
      bfr[j] = *(const bf16x8*)&Bs[wc * 64 + j * 16 + lm][lg << 3];
#pragma unroll
    for (int i = 0; i < 4; i++)
#pragma unroll
      for (int j = 0; j < 4; j++)
        acc[i][j] = __builtin_amdgcn_mfma_f32_16x16x32_bf16(af[i], bfr[j], acc[i][j], 0, 0, 0);
    __syncthreads();
  }

#pragma unroll
  for (int mt = 0; mt < 4; mt++) {
#pragma unroll
    for (int nt = 0; nt < 4; nt++) {
      long grow = m0 + wr * 64 + mt * 16 + lg * 4;
      long gcol = n0 + wc * 64 + nt * 16 + lm;
      float bv = bias ? bias[biasoff + gcol] : 0.f;
      if ((int)gcol < splitN) {
#pragma unroll
        for (int r = 0; r < 4; r++) {
          float v = acc[mt][nt][r] + bv;
          long idx = coff + (grow + r) * ldc + gcol;
          if (outBf) ((ushortt*)C)[idx] = f2b(v);
          else ((float*)C)[idx] = v;
        }
      } else if (c2vt) {
        int cc = (int)gcol - splitN;            // 0..767
        int hh = cc / 96, jj = cc - hh * 96;
#pragma unroll
        for (int r = 0; r < 4; r++) {
          float v = acc[mt][nt][r] + bv;
          long gr = grow + r;
          long b = gr >> 8, t = gr & 255;
          long idx = (((b * 8 + hh) * 128 + jj) << 8) + t;
          ((ushortt*)C2)[idx] = f2b(v);
        }
      } else {
        long col = gcol - splitN;
#pragma unroll
        for (int r = 0; r < 4; r++) {
          float v = acc[mt][nt][r] + bv;
          long idx = coff + (grow + r) * ldc2 + col;
          if (outBf2) ((ushortt*)C2)[idx] = f2b(v);
          else ((float*)C2)[idx] = v;
        }
      }
    }
  }
}

// ---------------------------------------------------------------------------
// fp32 GEMM (k2 only now).
// ---------------------------------------------------------------------------
__global__ __launch_bounds__(256) void mk_gemm(
    const float* __restrict__ A, const float* __restrict__ B,
    const float* __restrict__ bias, float* __restrict__ C,
    int M, int N, int K, int lda, int ldb, int ldc, int tilesN)
{
  int tile = blockIdx.x;
  int tm = tile / tilesN, tn = tile - tm * tilesN;
  int m0 = tm << 6, n0 = tn << 6;

  __shared__ float As[16][68];
  __shared__ float Bs[16][68];

  int tid = threadIdx.x;
  int tx = tid & 15, ty = tid >> 4;
  int lrow = tid >> 2;
  int lk = (tid & 3) << 2;

  float acc[4][4];
#pragma unroll
  for (int i = 0; i < 4; i++)
#pragma unroll
    for (int j = 0; j < 4; j++) acc[i][j] = 0.f;

  for (int k0 = 0; k0 < K; k0 += 16) {
    {
      int gm = m0 + lrow;
      float4 v = {0.f, 0.f, 0.f, 0.f};
      if (gm < M) v = *(const float4*)(A + (long)gm * lda + (k0 + lk));
      As[lk + 0][lrow] = v.x; As[lk + 1][lrow] = v.y;
      As[lk + 2][lrow] = v.z; As[lk + 3][lrow] = v.w;
    }
    {
      int gn = n0 + lrow;
      float4 v = {0.f, 0.f, 0.f, 0.f};
      if (gn < N) v = *(const float4*)(B + (long)gn * ldb + (k0 + lk));
      Bs[lk + 0][lrow] = v.x; Bs[lk + 1][lrow] = v.y;
      Bs[lk + 2][lrow] = v.z; Bs[lk + 3][lrow] = v.w;
    }
    __syncthreads();
#pragma unroll
    for (int kk = 0; kk < 16; kk++) {
      float4 a = *(const float4*)&As[kk][ty << 2];
      float4 b = *(const float4*)&Bs[kk][tx << 2];
      acc[0][0] += a.x * b.x; acc[0][1] += a.x * b.y; acc[0][2] += a.x * b.z; acc[0][3] += a.x * b.w;
      acc[1][0] += a.y * b.x; acc[1][1] += a.y * b.y; acc[1][2] += a.y * b.z; acc[1][3] += a.y * b.w;
      acc[2][0] += a.z * b.x; acc[2][1] += a.z * b.y; acc[2][2] += a.z * b.z; acc[2][3] += a.z * b.w;
      acc[3][0] += a.w * b.x; acc[3][1] += a.w * b.y; acc[3][2] += a.w * b.z; acc[3][3] += a.w * b.w;
    }
    __syncthreads();
  }

#pragma unroll
  for (int i = 0; i < 4; i++) {
    int gm = m0 + (ty << 2) + i;
    if (gm >= M) continue;
#pragma unroll
    for (int j = 0; j < 4; j++) {
      int gn = n0 + (tx << 2) + j;
      if (gn >= N) continue;
      float v = acc[i][j];
      if (bias) v += bias[gn];
      C[(long)gm * ldc + gn] = v;
    }
  }
}

// ---------------------------------------------------------------------------
// Softmax: fp32 scores in, bf16 att out (scale folded).
// ---------------------------------------------------------------------------
__global__ __launch_bounds__(256) void mk_softmax(const float* __restrict__ scores,
                                                  ushortt* __restrict__ att, float scale)
{
  int row = (blockIdx.x << 2) + (threadIdx.x >> 6);
  int lane = threadIdx.x & 63;
  const float* p = scores + (long)row * 256 + (lane << 2);
  float4 v = *(const float4*)p;
  float m = fmaxf(fmaxf(v.x, v.y), fmaxf(v.z, v.w));
#pragma unroll
  for (int o = 32; o; o >>= 1) m = fmaxf(m, __shfl_xor(m, o, 64));
  float sl = scale * LOG2E;
  v.x = fexp2(sl * (v.x - m));
  v.y = fexp2(sl * (v.y - m));
  v.z = fexp2(sl * (v.z - m));
  v.w = fexp2(sl * (v.w - m));
  float s = v.x + v.y + v.z + v.w;
#pragma unroll
  for (int o = 32; o; o >>= 1) s += __shfl_xor(s, o, 64);
  float r = 1.f / s;
  ushort4 o4;
  o4.x = f2b(v.x * r); o4.y = f2b(v.y * r); o4.z = f2b(v.z * r); o4.w = f2b(v.w * r);
  *(ushort4*)(att + (long)row * 256 + (lane << 2)) = o4;
}

// ---------------------------------------------------------------------------
__global__ __launch_bounds__(256) void mk_gates(const float* __restrict__ q2,
                                                const float* __restrict__ k2,
                                                float* __restrict__ gacc)
{
  __shared__ float k2p[8 * 808];
  int b = blockIdx.x >> 4, q = blockIdx.x & 15;
  for (int i = threadIdx.x; i < 6144; i += 256) {
    int e = i / 768, rem = i - e * 768;
    int h = rem / 96, j = rem - h * 96;
    k2p[e * 808 + h * 100 + j] = k2[i];
  }
  __syncthreads();
  const float scale = 0.10206207261596577f;
  int wid = threadIdx.x >> 6, lane = threadIdx.x & 63;
  int h = lane >> 3, e = lane & 7;
  const float* kp = &k2p[e * 808 + h * 100];
  float accL = 0.f;
#pragma unroll
  for (int ti = 0; ti < 4; ti++) {
    int l = q * 16 + wid * 4 + ti;
    const float* qh = q2 + ((long)b * LTOK + l) * DIMC + h * 96;
    float sum = 0.f;
#pragma unroll
    for (int j = 0; j < 96; j += 4) {
      float4 qv = *(const float4*)(qh + j);
      float4 kv = *(const float4*)(kp + j);
      sum += qv.x * kv.x + qv.y * kv.y + qv.z * kv.z + qv.w * kv.w;
    }
    float s = sum * scale;
    float mx = s;
#pragma unroll
    for (int o = 1; o <= 4; o <<= 1) mx = fmaxf(mx, __shfl_xor(mx, o, 64));
    float ex = fexp2((s - mx) * LOG2E);
    float se = ex;
#pragma unroll
    for (int o = 1; o <= 4; o <<= 1) se += __shfl_xor(se, o, 64);
    accL += ex / se;
  }
#pragma unroll
  for (int o = 8; o <= 32; o <<= 1) accL += __shfl_xor(accL, o, 64);
  __shared__ float red[4][8];
  if (lane < 8) red[wid][lane] = accL;
  __syncthreads();
  if (threadIdx.x < 8) {
    float v = red[0][threadIdx.x] + red[1][threadIdx.x] +
              red[2][threadIdx.x] + red[3][threadIdx.x];
    atomicAdd(&gacc[b * 8 + threadIdx.x], v);
  }
}

__global__ __launch_bounds__(64) void mk_gatetop(const float* __restrict__ gacc,
                                                 int* __restrict__ pe,
                                                 float* __restrict__ pw)
{
  int b = threadIdx.x;
  if (b >= 16) return;
  float g[8];
  for (int e = 0; e < 8; e++) g[e] = gacc[b * 8 + e] * (1.f / (8.f * 256.f));
  float mx = g[0];
  for (int e = 1; e < 8; e++) mx = fmaxf(mx, g[e]);
  float se = 0.f;
  for (int e = 0; e < 8; e++) { g[e] = expf(g[e] - mx); se += g[e]; }
  for (int e = 0; e < 8; e++) g[e] /= se;
  int i0 = 0;
  for (int e = 1; e < 8; e++) if (g[e] > g[i0]) i0 = e;
  int i1 = (i0 == 0) ? 1 : 0;
  for (int e = 0; e < 8; e++) if (e != i0 && g[e] > g[i1]) i1 = e;
  float w0 = 1.f / (1.f + expf(g[i1] - g[i0]));
  pe[2 * b] = i0; pe[2 * b + 1] = i1;
  pw[2 * b] = w0; pw[2 * b + 1] = 1.f - w0;
}

// ---------------------------------------------------------------------------
__global__ __launch_bounds__(768) void mk_conv(const float* __restrict__ xzx,
                                               const float* __restrict__ cw,
                                               const float* __restrict__ cb,
                                               const int* __restrict__ pe,
                                               float* __restrict__ xc)
{
  int blk = blockIdx.x;
  int p = blk >> 8, t = blk & 255;
  int e = pe[p];
  int h = t >> 4, w = t & 15;
  int c = threadIdx.x;
  const float* wp = cw + ((long)e * DIMC + c) * 9;
  float acc = cb[e * DIMC + c];
#pragma unroll
  for (int dh = 0; dh < 3; dh++) {
    int hh = h + dh - 1;
    if (hh < 0 || hh > 15) continue;
#pragma unroll
    for (int dw = 0; dw < 3; dw++) {
      int ww = w + dw - 1;
      if (ww < 0 || ww > 15) continue;
      acc += xzx[((long)p * LTOK + hh * 16 + ww) * DIMC + c] * wp[dh * 3 + dw];
    }
  }
  xc[((long)p * LTOK + t) * DIMC + c] = acc / (1.f + fexp2(-acc * LOG2E));
}

__device__ __forceinline__ int tmap(int dir, int s) {
  if (dir == 0) return s;
  if (dir == 1) return 255 - s;
  if (dir == 2) return ((s & 15) << 4) | (s >> 4);
  int u = 255 - s;
  return ((u & 15) << 4) | (u >> 4);
}

// ---------------------------------------------------------------------------
// dbl: wave-per-token, lanes on channel dim (coalesced). Output dblm2[p]:
// PER-DIR TRAVERSAL ORDER, bank-staggered: position s = tmap(dir, m)
// (involution), ss = (s&31)*8 + (s>>5).
//   dt image : dblm2[p*6144 + dir*1024 + ss*4 + 0..3]   (16B rows)
//   BC image : dblm2[p*6144 + 4096 + dir*512 + ss*2 + 0..1] (8B rows)
// The scan then reads base + i*128B / i*64B (immediate offsets, conflict-free:
// concurrent segs land 16B/8B apart).
// ---------------------------------------------------------------------------
__global__ __launch_bounds__(256) void mk_dbl(const float* __restrict__ xc,
                                              const float* __restrict__ xproj,
                                              const int* __restrict__ pe,
                                              float* __restrict__ dblm)
{
  int p = blockIdx.x >> 6;
  int tq = blockIdx.x & 63;
  int wid = threadIdx.x >> 6, lane = threadIdx.x & 63;
  int m = tq * 4 + wid;
  int e = pe[p];
  const float* xr = xc + ((long)p * LTOK + m) * DIMC;
  const float* wb = xproj + (long)e * 24 * DIMC;
  float4 xv[3];
#pragma unroll
  for (int j = 0; j < 3; j++) xv[j] = *(const float4*)(xr + j * 256 + lane * 4);
  float acc[24];
#pragma unroll
  for (int r = 0; r < 24; r++) {
    const float* wr = wb + r * DIMC;
    float s = 0.f;
#pragma unroll
    for (int j = 0; j < 3; j++) {
      float4 wv = *(const float4*)(wr + j * 256 + lane * 4);
      s += xv[j].x * wv.x + xv[j].y * wv.y + xv[j].z * wv.z + xv[j].w * wv.w;
    }
    acc[r] = s;
  }
#pragma unroll
  for (int r = 0; r < 24; r++)
#pragma unroll
    for (int o = 32; o; o >>= 1) acc[r] += __shfl_xor(acc[r], o, 64);
  if (lane == 0) {
    float* o = dblm + (long)p * 6144;
#pragma unroll
    for (int dd = 0; dd < 4; dd++) {
      int s = tmap(dd, m);
      int ss = ((s & 31) << 3) | (s >> 5);
      float* oa = o + dd * 1024 + ss * 4;
      oa[0] = acc[dd * 6 + 0]; oa[1] = acc[dd * 6 + 1];
      oa[2] = acc[dd * 6 + 2]; oa[3] = acc[dd * 6 + 3];
      float* ob = o + 4096 + dd * 512 + ss * 2;
      ob[0] = acc[dd * 6 + 4]; ob[1] = acc[dd * 6 + 5];
    }
  }
}

// ---------------------------------------------------------------------------
// Fused segmented scan, two-pass recompute, pre-permuted operands:
//  512 thr = 16c x 8seg x 4dir; 32 steps/segment; dir is wave-uniform.
//  Per step: ds_read_b128 (dt, imm offset i*128B) + ds_read_b64 (B/C, i*64B)
//  - zero address VALU, conflict-free; x read from global (L2-warm, keeps
//  LDS pipe light); yS stride-18 + toggle-2 (2-way = free).
//  LDS = 16K dtS + 8K bcS + 18K yS + 4K ahS + 64B = 47.4 KB -> 3 blocks/CU.
// ---------------------------------------------------------------------------
__global__ __launch_bounds__(512, 6) void mk_scan(const float* __restrict__ xc,
                                               const float* __restrict__ dblm,
                                               const float* __restrict__ dtw,
                                               const float* __restrict__ dtb,
                                               const float* __restrict__ Alog,
                                               const float* __restrict__ Dp,
                                               const int* __restrict__ pe,
                                               float* __restrict__ yac)
{
  __shared__ __attribute__((aligned(16))) float dtS[4096];   // [dir][ss][4]
  __shared__ __attribute__((aligned(16))) float bcS[2048];   // [dir][ss][2]
  __shared__ float yS[256 * 18];
  __shared__ float ahS[32][16][2];
  __shared__ float dsum[16];
  int blk = blockIdx.x;
  int p = blk / 48, cg = blk - p * 48;
  int c0 = cg << 4;
  int e = pe[p];
  int tid = threadIdx.x;
  // stage dblm2[p]: contiguous 24KB copy (already permuted + staggered)
  {
    const float4* src = (const float4*)(dblm + (long)p * 6144);
    float4* dA = (float4*)dtS;
    for (int i = tid; i < 1024; i += 512) dA[i] = src[i];
    if (tid < 512) ((float4*)bcS)[tid] = src[1024 + tid];
  }
  for (int i = tid; i < 256 * 18; i += 512) yS[i] = 0.f;
  if (tid < 16) {
    float s = 0.f;
#pragma unroll
    for (int dd = 0; dd < 4; dd++) s += Dp[(long)(e * 4 + dd) * DIMC + c0 + tid];
    dsum[tid] = s;
  }
  __syncthreads();

  int c = tid & 15;
  int rr = tid >> 4;
  int seg = rr & 7;
  int dir = rr >> 3;
  int d = c0 + c;
  const float* xcp = xc + (long)p * LTOK * DIMC + d;
  long pb = (long)(e * 4 + dir) * DIMC + d;
  float4 wv = *(const float4*)(dtw + pb * 4);
  wv.x *= LOG2E; wv.y *= LOG2E; wv.z *= LOG2E; wv.w *= LOG2E;
  float bdt = dtb[pb] * LOG2E;
  float Ad = -fexp2(Alog[pb] * LOG2E);
  int t0 = seg << 5;
  const float* dtP = &dtS[(dir << 10) + (seg << 2)];
  const float* bcP = &bcS[(dir << 9) + (seg << 1)];

  // pass 1: per-segment (ap, h) only
  float h = 0.f, ap = 1.f;
#pragma unroll
  for (int i = 0; i < 32; i++) {
    float4 dv = *(const float4*)(dtP + i * 32);
    float2 bc = *(const float2*)(bcP + i * 16);
    int mm = tmap(dir, t0 + i);
    float xv = xcp[(long)mm * DIMC];
    float xl = wv.x * dv.x + wv.y * dv.y + wv.z * dv.z + wv.w * dv.w + bdt;
    float te = fexp2(xl);
    float g = flog2(1.f + te);
    g = (xl > 86.f) ? xl : g;
    float de = fexp2(g * Ad);
    h = de * h + (g * LN2 * bc.x) * xv;
    ap *= de;
  }
  ahS[rr][c][0] = ap;
  ahS[rr][c][1] = h;
  __syncthreads();

  // batched segment combine
  float hh = 0.f;
  {
    int base = dir << 3;
    float av[8], hv[8];
#pragma unroll
    for (int j = 0; j < 8; j++) {
      av[j] = ahS[base + j][c][0];
      hv[j] = ahS[base + j][c][1];
    }
#pragma unroll
    for (int j = 0; j < 7; j++)
      if (j < seg) hh = av[j] * hh + hv[j];
  }

  // pass 2: recompute with carried state, emit C*h atomics
#pragma unroll
  for (int i = 0; i < 32; i++) {
    float4 dv = *(const float4*)(dtP + i * 32);
    float2 bc = *(const float2*)(bcP + i * 16);
    int mm = tmap(dir, t0 + i);
    float xv = xcp[(long)mm * DIMC];
    float xl = wv.x * dv.x + wv.y * dv.y + wv.z * dv.z + wv.w * dv.w + bdt;
    float te = fexp2(xl);
    float g = flog2(1.f + te);
    g = (xl > 86.f) ? xl : g;
    float de = fexp2(g * Ad);
    hh = de * hh + (g * LN2 * bc.x) * xv;
    atomicAdd(&yS[mm * 18 + c + (((mm >> 5) & 1) << 1)], hh * bc.y);
  }
  __syncthreads();

  const float* xcb = xc + (long)p * LTOK * DIMC + c0;
  float* yp = yac + (long)p * LTOK * DIMC + c0;
  for (int i = tid; i < 4096; i += 512) {
    int t = i >> 4, cz = i & 15;
    yp[(long)t * DIMC + cz] = yS[t * 18 + cz + (((t >> 5) & 1) << 1)] +
        xcb[(long)t * DIMC + cz] * dsum[cz];
  }
}

// ---------------------------------------------------------------------------
// LN + silu(z) + token partial-mean. 512 blocks = (p, 16-token slice).
// Accumulates into pre-zeroed eo via global atomics; 1/256 applied in mk_out.
// ---------------------------------------------------------------------------
__global__ __launch_bounds__(256) void mk_lnfin(const float* __restrict__ yac,
                                                const float* __restrict__ xzz,
                                                const float* __restrict__ lns,
                                                const float* __restrict__ lnb,
                                                const int* __restrict__ pe,
                                                float* __restrict__ eo)
{
  int blk = blockIdx.x;
  int p = blk >> 4, ts = blk & 15;
  int e = pe[p];
  int tid = threadIdx.x;
  int wid = tid >> 6, lane = tid & 63;
  float ls[12], lb[12], acc[12];
#pragma unroll
  for (int i = 0; i < 12; i++) {
    int d = i * 64 + lane;
    ls[i] = lns[e * DIMC + d];
    lb[i] = lnb[e * DIMC + d];
    acc[i] = 0.f;
  }
#pragma unroll
  for (int tt = 0; tt < 4; tt++) {
    int t = ts * 16 + wid * 4 + tt;
    const float* yr = yac + ((long)p * LTOK + t) * DIMC;
    const float* zr = xzz + ((long)p * LTOK + t) * DIMC;
    float v[12];
    float s = 0.f;
#pragma unroll
    for (int i = 0; i < 12; i++) { v[i] = yr[i * 64 + lane]; s += v[i]; }
#pragma unroll
    for (int o = 32; o; o >>= 1) s += __shfl_xor(s, o, 64);
    float mu = s * (1.f / 768.f);
    float sq = 0.f;
#pragma unroll
    for (int i = 0; i < 12; i++) { float dlt = v[i] - mu; sq += dlt * dlt; }
#pragma unroll
    for (int o = 32; o; o >>= 1) sq += __shfl_xor(sq, o, 64);
    float rs = rsqrtf(sq * (1.f / 768.f) + 1e-5f);
#pragma unroll
    for (int i = 0; i < 12; i++) {
      float y = (v[i] - mu) * rs * ls[i] + lb[i];
      float z = zr[i * 64 + lane];
      y *= z / (1.f + fexp2(-z * LOG2E));
      acc[i] += y;
    }
  }
  __shared__ float sacc[768];
  for (int j = tid; j < 768; j += 256) sacc[j] = 0.f;
  __syncthreads();
#pragma unroll
  for (int i = 0; i < 12; i++) atomicAdd(&sacc[i * 64 + lane], acc[i]);
  __syncthreads();
  for (int j = tid; j < 768; j += 256) atomicAdd(&eo[(long)p * DIMC + j], sacc[j]);
}

__global__ __launch_bounds__(768) void mk_out(const float* __restrict__ eo,
                                              const float* __restrict__ pw,
                                              float* __restrict__ out)
{
  int b = blockIdx.x, d = threadIdx.x;
  float v = pw[2 * b] * eo[(long)(2 * b) * DIMC + d] +
            pw[2 * b + 1] * eo[(long)(2 * b + 1) * DIMC + d];
  out[b * DIMC + d] = v * (1.f / 256.f);
}

// ---------------------------------------------------------------------------
extern "C" void kernel_launch(void* const* d_in, const int* in_sizes, int n_in,
                              void* d_out, int out_size, void* d_ws, size_t ws_size,
                              hipStream_t stream)
{
  const float* x        = (const float*)d_in[0];
  const float* sa_in_w  = (const float*)d_in[1];
  const float* sa_in_b  = (const float*)d_in[2];
  const float* sa_out_w = (const float*)d_in[3];
  const float* sa_out_b = (const float*)d_in[4];
  const float* ca_in_w  = (const float*)d_in[5];
  const float* ca_in_b  = (const float*)d_in[6];
  const float* eq       = (const float*)d_in[7];
  const float* e_in_w   = (const float*)d_in[8];
  const float* e_in_b   = (const float*)d_in[9];
  const float* e_conv_w = (const float*)d_in[10];
  const float* e_conv_b = (const float*)d_in[11];
  const float* e_xproj  = (const float*)d_in[12];
  const float* e_dtw    = (const float*)d_in[13];
  const float* e_dtb    = (const float*)d_in[14];
  const float* e_Alog   = (const float*)d_in[15];
  const float* e_D      = (const float*)d_in[16];
  const float* e_lns    = (const float*)d_in[17];
  const float* e_lnb    = (const float*)d_in[18];
  float* out = (float*)d_out;

  float* ws = (float*)d_ws;
  // ---- attention phase (float offsets) ----
  ushortt* qk_b   = (ushortt*)(ws + 0);          // 4096x1536 bf16  [0 .. 3,145,728)
  float*   scores = ws + 6291456;                // [6,291,456 .. 14,680,064)
  ushortt* dump_b = (ushortt*)(ws + 6291456);    // av dump (scores dead by then)
  ushortt* ctxa_b = (ushortt*)(ws + 7864320);    // 4096x768 bf16 [.. 9,437,184)
  ushortt* att_b  = (ushortt*)(ws + 14680064);   // 16x8x256x256 bf16 [.. 18,874,368)
  ushortt* vt_b   = (ushortt*)(ws + 18874368);   // 128x128x256 bf16 [.. 20,971,520)
  ushortt* xb     = (ushortt*)(ws + 20971520);   // [.. 22,544,384)
  ushortt* wqkv_b = (ushortt*)(ws + 22544384);   // [.. 23,429,120)
  ushortt* saow_b = (ushortt*)(ws + 23429120);   // [.. 23,724,032)
  ushortt* caw_b  = (ushortt*)(ws + 23724032);   // [.. 24,018,944)
  ushortt* ctx_b  = (ushortt*)(ws + 0);          // overlay qk_b (dead post-scores)
  float*   q2     = ws + 1572864;                // [.. 4,718,592) (qk_b dead)
  // ---- persistent smalls ----
  float*   k2     = ws + 25165824;
  int*     pe     = (int*)(ws + 25171968);
  float*   pw     = ws + 25172000;
  float*   eo     = ws + 25172032;               // [.. 25,196,608)
  float*   gacc   = ws + 25393216;               // [.. 25,393,344) peak 101.6MB
  // ---- expert phase ----
  float*   xz_x   = ws + 0;                      // [.. 6,291,456)
  float*   xz_z   = ws + 6291456;                // [.. 12,582,912) live -> lnfin
  ushortt* ew_b   = (ushortt*)(ws + 12582912);   // [.. 17,301,504) (scores/att dead)
  float*   xc     = ws + 12582912;               // [.. 18,874,368) after ew_b dead
  float*   yac    = ws + 18874368;               // [.. 25,165,824)
  float*   dblm   = ws + 0;                      // 32x6144 [.. 196,608) xz_x dead post-conv

  const float scale = 0.10206207261596577f;

  // 0. fused upfront casts: x, sa_in_w, sa_out_w, ca_in_w[:768]
  mk_mcast4<<<5952, 256, 0, stream>>>(x, xb, sa_in_w, wqkv_b, sa_out_w, saow_b,
                                      ca_in_w, caw_b);
  // 1. qkv MFMA: q,k -> qk_b bf16 (ld 1536); v -> vt_b transposed bf16
  mk_mfma<<<dim3(576, 1), 256, 0, stream>>>(xb, wqkv_b, sa_in_b, qk_b,
      768, 768, 768, 1536, 1, 0, 0, 0, 0, 0, 0, 0, nullptr, 18,
      1, 1536, vt_b, 0, 1, 1);
  // 2. scores = q @ k^T  (bf16 MFMA, K=96, Z=128, fp32 out)
  mk_mfma<<<dim3(4, 128), 256, 0, stream>>>(qk_b, qk_b + 768, nullptr, scores,
      96, 1536, 1536, 256, 8, 393216, 96, 393216, 96, 524288, 65536, 0, nullptr, 2,
      0, 1 << 30, nullptr, 0, 0, 0);
  // 3. softmax -> att_b bf16
  mk_softmax<<<8192, 256, 0, stream>>>(scores, att_b, scale);
  // 4. ctxa = att @ v  (bf16 MFMA via vt, N=96 + dump, Z=128)
  mk_mfma<<<dim3(2, 128), 256, 0, stream>>>(att_b, vt_b, nullptr, ctxa_b,
      256, 256, 256, 768, 8, 524288, 65536, 262144, 32768, 196608, 96, 0, nullptr, 1,
      1, 96, dump_b, 32, 1, 0);
  // 4b. cast expert weights (scores/att regions dead)
  mk_cast<<<9216, 256, 0, stream>>>(e_in_w, ew_b, 9437184);
  // 5. ctx = ctxa @ sa_out_w^T + b -> bf16
  mk_mfma<<<dim3(192, 1), 256, 0, stream>>>(ctxa_b, saow_b, sa_out_b, ctx_b,
      768, 768, 768, 768, 1, 0, 0, 0, 0, 0, 0, 0, nullptr, 6,
      1, 1 << 30, nullptr, 0, 0, 0);
  // 6. q2 = ctx @ ca_in_w[:768]^T + b (fp32 out)
  mk_mfma<<<dim3(192, 1), 256, 0, stream>>>(ctx_b, caw_b, ca_in_b, q2,
      768, 768, 768, 768, 1, 0, 0, 0, 0, 0, 0, 0, nullptr, 6,
      0, 1 << 30, nullptr, 0, 0, 0);
  // 7. k2 = eq @ ca_in_w[768:]^T + b  (8x768x768 fp32)
  mk_gemm<<<dim3(12, 1), 256, 0, stream>>>(eq, ca_in_w + 589824, ca_in_b + 768, k2,
      8, 768, 768, 768, 768, 768, 12);
  // 8. gate
  (void)hipMemsetAsync(gacc, 0, 128 * sizeof(float), stream);
  (void)hipMemsetAsync(eo, 0, 24576 * sizeof(float), stream);
  mk_gates<<<256, 256, 0, stream>>>(q2, k2, gacc);
  mk_gatetop<<<1, 64, 0, stream>>>(gacc, pe, pw);
  // 9. xz = x @ e_in_w[e]^T + b (Z=32 pair mode) split -> xz_x | xz_z
  mk_mfma<<<dim3(24, 32), 256, 0, stream>>>(xb, ew_b, e_in_b, xz_x,
      768, 768, 768, 768, 1, 196608, 0, 1179648, 0, 196608, 0, 1536, pe, 12,
      0, 768, xz_z, 768, 0, 0);
  // 10. depthwise conv + SiLU
  mk_conv<<<32 * 256, 768, 0, stream>>>(xz_x, e_conv_w, e_conv_b, pe, xc);
  // 11. dbl projections -> per-dir pre-permuted dblm2 (xz_x region dead)
  mk_dbl<<<2048, 256, 0, stream>>>(xc, e_xproj, pe, dblm);
  // 12. fused segmented scan (imm-offset LDS reads, 3 blocks/CU)
  mk_scan<<<1536, 512, 0, stream>>>(xc, dblm, e_dtw, e_dtb, e_Alog, e_D, pe, yac);
  // 13. LN + silu(z) + token mean (512 blocks, atomic into eo)
  mk_lnfin<<<512, 256, 0, stream>>>(yac, xz_z, e_lns, e_lnb, pe, eo);
  // 14. weighted top-2 combine (1/256 folded)
  mk_out<<<16, 768, 0, stream>>>(eo, pw, out);

  (void)in_sizes; (void)n_in; (void)out_size; (void)ws_size;
}

// Round 7
// 629.077 us; speedup vs baseline: 1.3473x; 1.3473x over previous
//
#include <hip/hip_runtime.h>
#include <hip/hip_bf16.h>

// MoEFSCIL: B=16, H=W=16, L=256, DIM=768, NH=8, HD=96, NEXP=8, TOPK=2.
// fp32 in/out. ALL GEMMs (incl. attention) bf16 MFMA; scan = fused segmented
// TWO-PASS recompute (8seg x 32step) with PRE-PERMUTED dblm2 (imm-offset LDS
// reads, zero addr VALU) + BOUNDED SCHEDULING WINDOW: 4-step chunks fenced by
// sched_barrier(0). r6 lesson: imm-offset loads with no fence => scheduler
// hoists all 32 steps' loads => ~190-float live range => 1GB scratch traffic
// (FETCH 357MB/WRITE 607MB) despite VGPR=40. Unified spill law: any >=30-float
// live window (hand-written OR scheduler-created) spills.

#define LTOK 256
#define DIMC 768

typedef unsigned short ushortt;
typedef __attribute__((ext_vector_type(8))) short bf16x8;
typedef __attribute__((ext_vector_type(4))) float f32x4;

#define LOG2E 1.44269504f
#define LN2   0.69314718f

__device__ __forceinline__ float fexp2(float x) { return __builtin_amdgcn_exp2f(x); }
__device__ __forceinline__ float flog2(float x) { return __builtin_amdgcn_logf(x); }

__device__ __forceinline__ ushortt f2b(float f) {
  union { float f; unsigned u; } c; c.f = f;
  unsigned r = (c.u + 0x7FFFu + ((c.u >> 16) & 1u)) >> 16;
  return (ushortt)r;
}

// ---------------------------------------------------------------------------
// Fused 4-tensor fp32->bf16 cast (x, sa_in_w, sa_out_w, ca_in_w[:768] rows).
// ---------------------------------------------------------------------------
__global__ __launch_bounds__(256) void mk_mcast4(
    const float* __restrict__ s0, ushortt* __restrict__ d0,
    const float* __restrict__ s1, ushortt* __restrict__ d1,
    const float* __restrict__ s2, ushortt* __restrict__ d2,
    const float* __restrict__ s3, ushortt* __restrict__ d3)
{
  long g = (long)blockIdx.x * 256 + threadIdx.x;   // float4 chunk id
  const float* s; ushortt* dst; long o;
  if (g < 786432)       { s = s0; dst = d0; o = g; }
  else if (g < 1228800) { s = s1; dst = d1; o = g - 786432; }
  else if (g < 1376256) { s = s2; dst = d2; o = g - 1228800; }
  else                  { s = s3; dst = d3; o = g - 1376256; }
  o <<= 2;
  float4 v = *(const float4*)(s + o);
  ushort4 w;
  w.x = f2b(v.x); w.y = f2b(v.y); w.z = f2b(v.z); w.w = f2b(v.w);
  *(ushort4*)(dst + o) = w;
}

__global__ __launch_bounds__(256) void mk_cast(const float* __restrict__ in,
                                               ushortt* __restrict__ outp, long n)
{
  long i = ((long)blockIdx.x * 256 + threadIdx.x) * 4;
  if (i + 3 < n) {
    float4 v = *(const float4*)(in + i);
    ushort4 o;
    o.x = f2b(v.x); o.y = f2b(v.y); o.z = f2b(v.z); o.w = f2b(v.w);
    *(ushort4*)(outp + i) = o;
  }
}

// ---------------------------------------------------------------------------
// bf16 MFMA GEMM: C[z] = A[z](M,K) @ B[z](N,K)^T + bias.
// Batch: pairExp (MoE) or zdiv (z1=z/zdiv, z2=z%zdiv) offsets.
// Column split at splitN: cols<splitN -> C (outBf), else C2 (outBf2, ldc2).
// c2vt: C2 written in vt layout [(b*8+h)*128 + j][t], b=row>>8, t=row&255,
//       h=(col-splitN)/96, j=(col-splitN)%96 (for the qkv v-transpose).
// ---------------------------------------------------------------------------
__global__ __launch_bounds__(256) void mk_mfma(
    const ushortt* __restrict__ A, const ushortt* __restrict__ B,
    const float* __restrict__ bias, void* __restrict__ C,
    int K, int lda, int ldb, int ldc,
    int zdiv, long sA1, long sA2, long sB1, long sB2, long sC1, long sC2,
    long sBias,
    const int* __restrict__ pairExp, int tilesN,
    int outBf, int splitN, void* __restrict__ C2, int ldc2, int outBf2, int c2vt)
{
  int z = blockIdx.y;
  long aoff, boff, coff, biasoff = 0;
  if (pairExp) {
    int e = pairExp[z];
    aoff = (long)(z >> 1) * sA1; boff = (long)e * sB1;
    coff = (long)z * sC1; biasoff = (long)e * sBias;
  } else {
    int z1 = z / zdiv, z2 = z - z1 * zdiv;
    aoff = (long)z1 * sA1 + (long)z2 * sA2;
    boff = (long)z1 * sB1 + (long)z2 * sB2;
    coff = (long)z1 * sC1 + (long)z2 * sC2;
  }
  int tile = blockIdx.x;
  int tm = tile / tilesN, tn = tile - tm * tilesN;
  long m0 = (long)tm << 7, n0 = (long)tn << 7;

  __shared__ ushortt As[128][40];
  __shared__ ushortt Bs[128][40];

  int tid = threadIdx.x;
  int lane = tid & 63, wvi = tid >> 6;
  int wr = wvi >> 1, wc = wvi & 1;
  int lm = lane & 15, lg = lane >> 4;

  f32x4 zero4 = {0.f, 0.f, 0.f, 0.f};
  f32x4 acc[4][4];
#pragma unroll
  for (int i = 0; i < 4; i++)
#pragma unroll
    for (int j = 0; j < 4; j++) acc[i][j] = zero4;

  const ushortt* Ab = A + aoff;
  const ushortt* Bb = B + boff;

  for (int k0 = 0; k0 < K; k0 += 32) {
#pragma unroll
    for (int h = 0; h < 2; h++) {
      int q = tid + h * 256;
      int row = q >> 2, ck = (q & 3) << 3;
      *(uint4*)&As[row][ck] = *(const uint4*)(Ab + (m0 + row) * lda + k0 + ck);
      *(uint4*)&Bs[row][ck] = *(const uint4*)(Bb + (n0 + row) * ldb + k0 + ck);
    }
    __syncthreads();
    bf16x8 af[4], bfr[4];
#pragma unroll
    for (int i = 0; i < 4; i++)
      af[i] = *(const bf16x8*)&As[wr * 64 + i * 16 + lm][lg << 3];
#pragma unroll
    for (int j = 0; j < 4; j++)
      bfr[j] = *(const bf16x8*)&Bs[wc * 64 + j * 16 + lm][lg << 3];
#pragma unroll
    for (int i = 0; i < 4; i++)
#pragma unroll
      for (int j = 0; j < 4; j++)
        acc[i][j] = __builtin_amdgcn_mfma_f32_16x16x32_bf16(af[i], bfr[j], acc[i][j], 0, 0, 0);
    __syncthreads();
  }

#pragma unroll
  for (int mt = 0; mt < 4; mt++) {
#pragma unroll
    for (int nt = 0; nt < 4; nt++) {
      long grow = m0 + wr * 64 + mt * 16 + lg * 4;
      long gcol = n0 + wc * 64 + nt * 16 + lm;
      float bv = bias ? bias[biasoff + gcol] : 0.f;
      if ((int)gcol < splitN) {
#pragma unroll
        for (int r = 0; r < 4; r++) {
          float v = acc[mt][nt][r] + bv;
          long idx = coff + (grow + r) * ldc + gcol;
          if (outBf) ((ushortt*)C)[idx] = f2b(v);
          else ((float*)C)[idx] = v;
        }
      } else if (c2vt) {
        int cc = (int)gcol - splitN;            // 0..767
        int hh = cc / 96, jj = cc - hh * 96;
#pragma unroll
        for (int r = 0; r < 4; r++) {
          float v = acc[mt][nt][r] + bv;
          long gr = grow + r;
          long b = gr >> 8, t = gr & 255;
          long idx = (((b * 8 + hh) * 128 + jj) << 8) + t;
          ((ushortt*)C2)[idx] = f2b(v);
        }
      } else {
        long col = gcol - splitN;
#pragma unroll
        for (int r = 0; r < 4; r++) {
          float v = acc[mt][nt][r] + bv;
          long idx = coff + (grow + r) * ldc2 + col;
          if (outBf2) ((ushortt*)C2)[idx] = f2b(v);
          else ((float*)C2)[idx] = v;
        }
      }
    }
  }
}

// ---------------------------------------------------------------------------
// fp32 GEMM (k2 only now).
// ---------------------------------------------------------------------------
__global__ __launch_bounds__(256) void mk_gemm(
    const float* __restrict__ A, const float* __restrict__ B,
    const float* __restrict__ bias, float* __restrict__ C,
    int M, int N, int K, int lda, int ldb, int ldc, int tilesN)
{
  int tile = blockIdx.x;
  int tm = tile / tilesN, tn = tile - tm * tilesN;
  int m0 = tm << 6, n0 = tn << 6;

  __shared__ float As[16][68];
  __shared__ float Bs[16][68];

  int tid = threadIdx.x;
  int tx = tid & 15, ty = tid >> 4;
  int lrow = tid >> 2;
  int lk = (tid & 3) << 2;

  float acc[4][4];
#pragma unroll
  for (int i = 0; i < 4; i++)
#pragma unroll
    for (int j = 0; j < 4; j++) acc[i][j] = 0.f;

  for (int k0 = 0; k0 < K; k0 += 16) {
    {
      int gm = m0 + lrow;
      float4 v = {0.f, 0.f, 0.f, 0.f};
      if (gm < M) v = *(const float4*)(A + (long)gm * lda + (k0 + lk));
      As[lk + 0][lrow] = v.x; As[lk + 1][lrow] = v.y;
      As[lk + 2][lrow] = v.z; As[lk + 3][lrow] = v.w;
    }
    {
      int gn = n0 + lrow;
      float4 v = {0.f, 0.f, 0.f, 0.f};
      if (gn < N) v = *(const float4*)(B + (long)gn * ldb + (k0 + lk));
      Bs[lk + 0][lrow] = v.x; Bs[lk + 1][lrow] = v.y;
      Bs[lk + 2][lrow] = v.z; Bs[lk + 3][lrow] = v.w;
    }
    __syncthreads();
#pragma unroll
    for (int kk = 0; kk < 16; kk++) {
      float4 a = *(const float4*)&As[kk][ty << 2];
      float4 b = *(const float4*)&Bs[kk][tx << 2];
      acc[0][0] += a.x * b.x; acc[0][1] += a.x * b.y; acc[0][2] += a.x * b.z; acc[0][3] += a.x * b.w;
      acc[1][0] += a.y * b.x; acc[1][1] += a.y * b.y; acc[1][2] += a.y * b.z; acc[1][3] += a.y * b.w;
      acc[2][0] += a.z * b.x; acc[2][1] += a.z * b.y; acc[2][2] += a.z * b.z; acc[2][3] += a.z * b.w;
      acc[3][0] += a.w * b.x; acc[3][1] += a.w * b.y; acc[3][2] += a.w * b.z; acc[3][3] += a.w * b.w;
    }
    __syncthreads();
  }

#pragma unroll
  for (int i = 0; i < 4; i++) {
    int gm = m0 + (ty << 2) + i;
    if (gm >= M) continue;
#pragma unroll
    for (int j = 0; j < 4; j++) {
      int gn = n0 + (tx << 2) + j;
      if (gn >= N) continue;
      float v = acc[i][j];
      if (bias) v += bias[gn];
      C[(long)gm * ldc + gn] = v;
    }
  }
}

// ---------------------------------------------------------------------------
// Softmax: fp32 scores in, bf16 att out (scale folded).
// ---------------------------------------------------------------------------
__global__ __launch_bounds__(256) void mk_softmax(const float* __restrict__ scores,
                                                  ushortt* __restrict__ att, float scale)
{
  int row = (blockIdx.x << 2) + (threadIdx.x >> 6);
  int lane = threadIdx.x & 63;
  const float* p = scores + (long)row * 256 + (lane << 2);
  float4 v = *(const float4*)p;
  float m = fmaxf(fmaxf(v.x, v.y), fmaxf(v.z, v.w));
#pragma unroll
  for (int o = 32; o; o >>= 1) m = fmaxf(m, __shfl_xor(m, o, 64));
  float sl = scale * LOG2E;
  v.x = fexp2(sl * (v.x - m));
  v.y = fexp2(sl * (v.y - m));
  v.z = fexp2(sl * (v.z - m));
  v.w = fexp2(sl * (v.w - m));
  float s = v.x + v.y + v.z + v.w;
#pragma unroll
  for (int o = 32; o; o >>= 1) s += __shfl_xor(s, o, 64);
  float r = 1.f / s;
  ushort4 o4;
  o4.x = f2b(v.x * r); o4.y = f2b(v.y * r); o4.z = f2b(v.z * r); o4.w = f2b(v.w * r);
  *(ushort4*)(att + (long)row * 256 + (lane << 2)) = o4;
}

// ---------------------------------------------------------------------------
__global__ __launch_bounds__(256) void mk_gates(const float* __restrict__ q2,
                                                const float* __restrict__ k2,
                                                float* __restrict__ gacc)
{
  __shared__ float k2p[8 * 808];
  int b = blockIdx.x >> 4, q = blockIdx.x & 15;
  for (int i = threadIdx.x; i < 6144; i += 256) {
    int e = i / 768, rem = i - e * 768;
    int h = rem / 96, j = rem - h * 96;
    k2p[e * 808 + h * 100 + j] = k2[i];
  }
  __syncthreads();
  const float scale = 0.10206207261596577f;
  int wid = threadIdx.x >> 6, lane = threadIdx.x & 63;
  int h = lane >> 3, e = lane & 7;
  const float* kp = &k2p[e * 808 + h * 100];
  float accL = 0.f;
#pragma unroll
  for (int ti = 0; ti < 4; ti++) {
    int l = q * 16 + wid * 4 + ti;
    const float* qh = q2 + ((long)b * LTOK + l) * DIMC + h * 96;
    float sum = 0.f;
#pragma unroll
    for (int j = 0; j < 96; j += 4) {
      float4 qv = *(const float4*)(qh + j);
      float4 kv = *(const float4*)(kp + j);
      sum += qv.x * kv.x + qv.y * kv.y + qv.z * kv.z + qv.w * kv.w;
    }
    float s = sum * scale;
    float mx = s;
#pragma unroll
    for (int o = 1; o <= 4; o <<= 1) mx = fmaxf(mx, __shfl_xor(mx, o, 64));
    float ex = fexp2((s - mx) * LOG2E);
    float se = ex;
#pragma unroll
    for (int o = 1; o <= 4; o <<= 1) se += __shfl_xor(se, o, 64);
    accL += ex / se;
  }
#pragma unroll
  for (int o = 8; o <= 32; o <<= 1) accL += __shfl_xor(accL, o, 64);
  __shared__ float red[4][8];
  if (lane < 8) red[wid][lane] = accL;
  __syncthreads();
  if (threadIdx.x < 8) {
    float v = red[0][threadIdx.x] + red[1][threadIdx.x] +
              red[2][threadIdx.x] + red[3][threadIdx.x];
    atomicAdd(&gacc[b * 8 + threadIdx.x], v);
  }
}

__global__ __launch_bounds__(64) void mk_gatetop(const float* __restrict__ gacc,
                                                 int* __restrict__ pe,
                                                 float* __restrict__ pw)
{
  int b = threadIdx.x;
  if (b >= 16) return;
  float g[8];
  for (int e = 0; e < 8; e++) g[e] = gacc[b * 8 + e] * (1.f / (8.f * 256.f));
  float mx = g[0];
  for (int e = 1; e < 8; e++) mx = fmaxf(mx, g[e]);
  float se = 0.f;
  for (int e = 0; e < 8; e++) { g[e] = expf(g[e] - mx); se += g[e]; }
  for (int e = 0; e < 8; e++) g[e] /= se;
  int i0 = 0;
  for (int e = 1; e < 8; e++) if (g[e] > g[i0]) i0 = e;
  int i1 = (i0 == 0) ? 1 : 0;
  for (int e = 0; e < 8; e++) if (e != i0 && g[e] > g[i1]) i1 = e;
  float w0 = 1.f / (1.f + expf(g[i1] - g[i0]));
  pe[2 * b] = i0; pe[2 * b + 1] = i1;
  pw[2 * b] = w0; pw[2 * b + 1] = 1.f - w0;
}

// ---------------------------------------------------------------------------
__global__ __launch_bounds__(768) void mk_conv(const float* __restrict__ xzx,
                                               const float* __restrict__ cw,
                                               const float* __restrict__ cb,
                                               const int* __restrict__ pe,
                                               float* __restrict__ xc)
{
  int blk = blockIdx.x;
  int p = blk >> 8, t = blk & 255;
  int e = pe[p];
  int h = t >> 4, w = t & 15;
  int c = threadIdx.x;
  const float* wp = cw + ((long)e * DIMC + c) * 9;
  float acc = cb[e * DIMC + c];
#pragma unroll
  for (int dh = 0; dh < 3; dh++) {
    int hh = h + dh - 1;
    if (hh < 0 || hh > 15) continue;
#pragma unroll
    for (int dw = 0; dw < 3; dw++) {
      int ww = w + dw - 1;
      if (ww < 0 || ww > 15) continue;
      acc += xzx[((long)p * LTOK + hh * 16 + ww) * DIMC + c] * wp[dh * 3 + dw];
    }
  }
  xc[((long)p * LTOK + t) * DIMC + c] = acc / (1.f + fexp2(-acc * LOG2E));
}

__device__ __forceinline__ int tmap(int dir, int s) {
  if (dir == 0) return s;
  if (dir == 1) return 255 - s;
  if (dir == 2) return ((s & 15) << 4) | (s >> 4);
  int u = 255 - s;
  return ((u & 15) << 4) | (u >> 4);
}

// ---------------------------------------------------------------------------
// dbl: wave-per-token, lanes on channel dim (coalesced). Output dblm2[p]:
// PER-DIR TRAVERSAL ORDER, bank-staggered: position s = tmap(dir, m)
// (involution), ss = (s&31)*8 + (s>>5).
//   dt image : dblm2[p*6144 + dir*1024 + ss*4 + 0..3]   (16B rows)
//   BC image : dblm2[p*6144 + 4096 + dir*512 + ss*2 + 0..1] (8B rows)
// The scan then reads base + i*128B / i*64B (immediate offsets, conflict-free:
// concurrent segs land 16B/8B apart).
// ---------------------------------------------------------------------------
__global__ __launch_bounds__(256) void mk_dbl(const float* __restrict__ xc,
                                              const float* __restrict__ xproj,
                                              const int* __restrict__ pe,
                                              float* __restrict__ dblm)
{
  int p = blockIdx.x >> 6;
  int tq = blockIdx.x & 63;
  int wid = threadIdx.x >> 6, lane = threadIdx.x & 63;
  int m = tq * 4 + wid;
  int e = pe[p];
  const float* xr = xc + ((long)p * LTOK + m) * DIMC;
  const float* wb = xproj + (long)e * 24 * DIMC;
  float4 xv[3];
#pragma unroll
  for (int j = 0; j < 3; j++) xv[j] = *(const float4*)(xr + j * 256 + lane * 4);
  float acc[24];
#pragma unroll
  for (int r = 0; r < 24; r++) {
    const float* wr = wb + r * DIMC;
    float s = 0.f;
#pragma unroll
    for (int j = 0; j < 3; j++) {
      float4 wv = *(const float4*)(wr + j * 256 + lane * 4);
      s += xv[j].x * wv.x + xv[j].y * wv.y + xv[j].z * wv.z + xv[j].w * wv.w;
    }
    acc[r] = s;
  }
#pragma unroll
  for (int r = 0; r < 24; r++)
#pragma unroll
    for (int o = 32; o; o >>= 1) acc[r] += __shfl_xor(acc[r], o, 64);
  if (lane == 0) {
    float* o = dblm + (long)p * 6144;
#pragma unroll
    for (int dd = 0; dd < 4; dd++) {
      int s = tmap(dd, m);
      int ss = ((s & 31) << 3) | (s >> 5);
      float* oa = o + dd * 1024 + ss * 4;
      oa[0] = acc[dd * 6 + 0]; oa[1] = acc[dd * 6 + 1];
      oa[2] = acc[dd * 6 + 2]; oa[3] = acc[dd * 6 + 3];
      float* ob = o + 4096 + dd * 512 + ss * 2;
      ob[0] = acc[dd * 6 + 4]; ob[1] = acc[dd * 6 + 5];
    }
  }
}

// ---------------------------------------------------------------------------
// Fused segmented scan, two-pass recompute, pre-permuted operands, FENCED:
//  512 thr = 16c x 8seg x 4dir; 32 steps/segment in 4-step chunks; each chunk
//  ends with sched_barrier(0) so the scheduler cannot hoist loads across
//  chunks (bounded ~4-step live window -> no scratch). Per step:
//  ds_read_b128 (dt) + ds_read_b64 (B/C) at base+tb*chunk+imm, conflict-free.
//  LDS = 16K dtS + 8K bcS + 18K yS + 4K ahS + 64B = 47.4 KB -> 3 blocks/CU.
// ---------------------------------------------------------------------------
__global__ __launch_bounds__(512, 6) void mk_scan(const float* __restrict__ xc,
                                               const float* __restrict__ dblm,
                                               const float* __restrict__ dtw,
                                               const float* __restrict__ dtb,
                                               const float* __restrict__ Alog,
                                               const float* __restrict__ Dp,
                                               const int* __restrict__ pe,
                                               float* __restrict__ yac)
{
  __shared__ __attribute__((aligned(16))) float dtS[4096];   // [dir][ss][4]
  __shared__ __attribute__((aligned(16))) float bcS[2048];   // [dir][ss][2]
  __shared__ float yS[256 * 18];
  __shared__ float ahS[32][16][2];
  __shared__ float dsum[16];
  int blk = blockIdx.x;
  int p = blk / 48, cg = blk - p * 48;
  int c0 = cg << 4;
  int e = pe[p];
  int tid = threadIdx.x;
  // stage dblm2[p]: contiguous 24KB copy (already permuted + staggered)
  {
    const float4* src = (const float4*)(dblm + (long)p * 6144);
    float4* dA = (float4*)dtS;
    for (int i = tid; i < 1024; i += 512) dA[i] = src[i];
    if (tid < 512) ((float4*)bcS)[tid] = src[1024 + tid];
  }
  for (int i = tid; i < 256 * 18; i += 512) yS[i] = 0.f;
  if (tid < 16) {
    float s = 0.f;
#pragma unroll
    for (int dd = 0; dd < 4; dd++) s += Dp[(long)(e * 4 + dd) * DIMC + c0 + tid];
    dsum[tid] = s;
  }
  __syncthreads();

  int c = tid & 15;
  int rr = tid >> 4;
  int seg = rr & 7;
  int dir = rr >> 3;
  int d = c0 + c;
  const float* xcp = xc + (long)p * LTOK * DIMC + d;
  long pb = (long)(e * 4 + dir) * DIMC + d;
  float4 wv = *(const float4*)(dtw + pb * 4);
  wv.x *= LOG2E; wv.y *= LOG2E; wv.z *= LOG2E; wv.w *= LOG2E;
  float bdt = dtb[pb] * LOG2E;
  float Ad = -fexp2(Alog[pb] * LOG2E);
  int t0 = seg << 5;
  const float* dtP = &dtS[(dir << 10) + (seg << 2)];
  const float* bcP = &bcS[(dir << 9) + (seg << 1)];

  // pass 1: per-segment (ap, h) only; 4-step fenced chunks
  float h = 0.f, ap = 1.f;
#pragma unroll 1
  for (int tb = 0; tb < 32; tb += 4) {
#pragma unroll
    for (int u = 0; u < 4; u++) {
      int i = tb + u;
      float4 dv = *(const float4*)(dtP + i * 32);
      float2 bc = *(const float2*)(bcP + i * 16);
      int mm = tmap(dir, t0 + i);
      float xv = xcp[(long)mm * DIMC];
      float xl = wv.x * dv.x + wv.y * dv.y + wv.z * dv.z + wv.w * dv.w + bdt;
      float te = fexp2(xl);
      float g = flog2(1.f + te);
      g = (xl > 86.f) ? xl : g;
      float de = fexp2(g * Ad);
      h = de * h + (g * LN2 * bc.x) * xv;
      ap *= de;
    }
    __builtin_amdgcn_sched_barrier(0);
  }
  ahS[rr][c][0] = ap;
  ahS[rr][c][1] = h;
  __syncthreads();

  // batched segment combine
  float hh = 0.f;
  {
    int base = dir << 3;
    float av[8], hv[8];
#pragma unroll
    for (int j = 0; j < 8; j++) {
      av[j] = ahS[base + j][c][0];
      hv[j] = ahS[base + j][c][1];
    }
#pragma unroll
    for (int j = 0; j < 7; j++)
      if (j < seg) hh = av[j] * hh + hv[j];
  }

  // pass 2: recompute with carried state, emit C*h atomics; fenced chunks
#pragma unroll 1
  for (int tb = 0; tb < 32; tb += 4) {
#pragma unroll
    for (int u = 0; u < 4; u++) {
      int i = tb + u;
      float4 dv = *(const float4*)(dtP + i * 32);
      float2 bc = *(const float2*)(bcP + i * 16);
      int mm = tmap(dir, t0 + i);
      float xv = xcp[(long)mm * DIMC];
      float xl = wv.x * dv.x + wv.y * dv.y + wv.z * dv.z + wv.w * dv.w + bdt;
      float te = fexp2(xl);
      float g = flog2(1.f + te);
      g = (xl > 86.f) ? xl : g;
      float de = fexp2(g * Ad);
      hh = de * hh + (g * LN2 * bc.x) * xv;
      atomicAdd(&yS[mm * 18 + c + (((mm >> 5) & 1) << 1)], hh * bc.y);
    }
    __builtin_amdgcn_sched_barrier(0);
  }
  __syncthreads();

  const float* xcb = xc + (long)p * LTOK * DIMC + c0;
  float* yp = yac + (long)p * LTOK * DIMC + c0;
  for (int i = tid; i < 4096; i += 512) {
    int t = i >> 4, cz = i & 15;
    yp[(long)t * DIMC + cz] = yS[t * 18 + cz + (((t >> 5) & 1) << 1)] +
        xcb[(long)t * DIMC + cz] * dsum[cz];
  }
}

// ---------------------------------------------------------------------------
// LN + silu(z) + token partial-mean. 512 blocks = (p, 16-token slice).
// Accumulates into pre-zeroed eo via global atomics; 1/256 applied in mk_out.
// ---------------------------------------------------------------------------
__global__ __launch_bounds__(256) void mk_lnfin(const float* __restrict__ yac,
                                                const float* __restrict__ xzz,
                                                const float* __restrict__ lns,
                                                const float* __restrict__ lnb,
                                                const int* __restrict__ pe,
                                                float* __restrict__ eo)
{
  int blk = blockIdx.x;
  int p = blk >> 4, ts = blk & 15;
  int e = pe[p];
  int tid = threadIdx.x;
  int wid = tid >> 6, lane = tid & 63;
  float ls[12], lb[12], acc[12];
#pragma unroll
  for (int i = 0; i < 12; i++) {
    int d = i * 64 + lane;
    ls[i] = lns[e * DIMC + d];
    lb[i] = lnb[e * DIMC + d];
    acc[i] = 0.f;
  }
#pragma unroll
  for (int tt = 0; tt < 4; tt++) {
    int t = ts * 16 + wid * 4 + tt;
    const float* yr = yac + ((long)p * LTOK + t) * DIMC;
    const float* zr = xzz + ((long)p * LTOK + t) * DIMC;
    float v[12];
    float s = 0.f;
#pragma unroll
    for (int i = 0; i < 12; i++) { v[i] = yr[i * 64 + lane]; s += v[i]; }
#pragma unroll
    for (int o = 32; o; o >>= 1) s += __shfl_xor(s, o, 64);
    float mu = s * (1.f / 768.f);
    float sq = 0.f;
#pragma unroll
    for (int i = 0; i < 12; i++) { float dlt = v[i] - mu; sq += dlt * dlt; }
#pragma unroll
    for (int o = 32; o; o >>= 1) sq += __shfl_xor(sq, o, 64);
    float rs = rsqrtf(sq * (1.f / 768.f) + 1e-5f);
#pragma unroll
    for (int i = 0; i < 12; i++) {
      float y = (v[i] - mu) * rs * ls[i] + lb[i];
      float z = zr[i * 64 + lane];
      y *= z / (1.f + fexp2(-z * LOG2E));
      acc[i] += y;
    }
  }
  __shared__ float sacc[768];
  for (int j = tid; j < 768; j += 256) sacc[j] = 0.f;
  __syncthreads();
#pragma unroll
  for (int i = 0; i < 12; i++) atomicAdd(&sacc[i * 64 + lane], acc[i]);
  __syncthreads();
  for (int j = tid; j < 768; j += 256) atomicAdd(&eo[(long)p * DIMC + j], sacc[j]);
}

__global__ __launch_bounds__(768) void mk_out(const float* __restrict__ eo,
                                              const float* __restrict__ pw,
                                              float* __restrict__ out)
{
  int b = blockIdx.x, d = threadIdx.x;
  float v = pw[2 * b] * eo[(long)(2 * b) * DIMC + d] +
            pw[2 * b + 1] * eo[(long)(2 * b + 1) * DIMC + d];
  out[b * DIMC + d] = v * (1.f / 256.f);
}

// ---------------------------------------------------------------------------
extern "C" void kernel_launch(void* const* d_in, const int* in_sizes, int n_in,
                              void* d_out, int out_size, void* d_ws, size_t ws_size,
                              hipStream_t stream)
{
  const float* x        = (const float*)d_in[0];
  const float* sa_in_w  = (const float*)d_in[1];
  const float* sa_in_b  = (const float*)d_in[2];
  const float* sa_out_w = (const float*)d_in[3];
  const float* sa_out_b = (const float*)d_in[4];
  const float* ca_in_w  = (const float*)d_in[5];
  const float* ca_in_b  = (const float*)d_in[6];
  const float* eq       = (const float*)d_in[7];
  const float* e_in_w   = (const float*)d_in[8];
  const float* e_in_b   = (const float*)d_in[9];
  const float* e_conv_w = (const float*)d_in[10];
  const float* e_conv_b = (const float*)d_in[11];
  const float* e_xproj  = (const float*)d_in[12];
  const float* e_dtw    = (const float*)d_in[13];
  const float* e_dtb    = (const float*)d_in[14];
  const float* e_Alog   = (const float*)d_in[15];
  const float* e_D      = (const float*)d_in[16];
  const float* e_lns    = (const float*)d_in[17];
  const float* e_lnb    = (const float*)d_in[18];
  float* out = (float*)d_out;

  float* ws = (float*)d_ws;
  // ---- attention phase (float offsets) ----
  ushortt* qk_b   = (ushortt*)(ws + 0);          // 4096x1536 bf16  [0 .. 3,145,728)
  float*   scores = ws + 6291456;                // [6,291,456 .. 14,680,064)
  ushortt* dump_b = (ushortt*)(ws + 6291456);    // av dump (scores dead by then)
  ushortt* ctxa_b = (ushortt*)(ws + 7864320);    // 4096x768 bf16 [.. 9,437,184)
  ushortt* att_b  = (ushortt*)(ws + 14680064);   // 16x8x256x256 bf16 [.. 18,874,368)
  ushortt* vt_b   = (ushortt*)(ws + 18874368);   // 128x128x256 bf16 [.. 20,971,520)
  ushortt* xb     = (ushortt*)(ws + 20971520);   // [.. 22,544,384)
  ushortt* wqkv_b = (ushortt*)(ws + 22544384);   // [.. 23,429,120)
  ushortt* saow_b = (ushortt*)(ws + 23429120);   // [.. 23,724,032)
  ushortt* caw_b  = (ushortt*)(ws + 23724032);   // [.. 24,018,944)
  ushortt* ctx_b  = (ushortt*)(ws + 0);          // overlay qk_b (dead post-scores)
  float*   q2     = ws + 1572864;                // [.. 4,718,592) (qk_b dead)
  // ---- persistent smalls ----
  float*   k2     = ws + 25165824;
  int*     pe     = (int*)(ws + 25171968);
  float*   pw     = ws + 25172000;
  float*   eo     = ws + 25172032;               // [.. 25,196,608)
  float*   gacc   = ws + 25393216;               // [.. 25,393,344) peak 101.6MB
  // ---- expert phase ----
  float*   xz_x   = ws + 0;                      // [.. 6,291,456)
  float*   xz_z   = ws + 6291456;                // [.. 12,582,912) live -> lnfin
  ushortt* ew_b   = (ushortt*)(ws + 12582912);   // [.. 17,301,504) (scores/att dead)
  float*   xc     = ws + 12582912;               // [.. 18,874,368) after ew_b dead
  float*   yac    = ws + 18874368;               // [.. 25,165,824)
  float*   dblm   = ws + 0;                      // 32x6144 [.. 196,608) xz_x dead post-conv

  const float scale = 0.10206207261596577f;

  // 0. fused upfront casts: x, sa_in_w, sa_out_w, ca_in_w[:768]
  mk_mcast4<<<5952, 256, 0, stream>>>(x, xb, sa_in_w, wqkv_b, sa_out_w, saow_b,
                                      ca_in_w, caw_b);
  // 1. qkv MFMA: q,k -> qk_b bf16 (ld 1536); v -> vt_b transposed bf16
  mk_mfma<<<dim3(576, 1), 256, 0, stream>>>(xb, wqkv_b, sa_in_b, qk_b,
      768, 768, 768, 1536, 1, 0, 0, 0, 0, 0, 0, 0, nullptr, 18,
      1, 1536, vt_b, 0, 1, 1);
  // 2. scores = q @ k^T  (bf16 MFMA, K=96, Z=128, fp32 out)
  mk_mfma<<<dim3(4, 128), 256, 0, stream>>>(qk_b, qk_b + 768, nullptr, scores,
      96, 1536, 1536, 256, 8, 393216, 96, 393216, 96, 524288, 65536, 0, nullptr, 2,
      0, 1 << 30, nullptr, 0, 0, 0);
  // 3. softmax -> att_b bf16
  mk_softmax<<<8192, 256, 0, stream>>>(scores, att_b, scale);
  // 4. ctxa = att @ v  (bf16 MFMA via vt, N=96 + dump, Z=128)
  mk_mfma<<<dim3(2, 128), 256, 0, stream>>>(att_b, vt_b, nullptr, ctxa_b,
      256, 256, 256, 768, 8, 524288, 65536, 262144, 32768, 196608, 96, 0, nullptr, 1,
      1, 96, dump_b, 32, 1, 0);
  // 4b. cast expert weights (scores/att regions dead)
  mk_cast<<<9216, 256, 0, stream>>>(e_in_w, ew_b, 9437184);
  // 5. ctx = ctxa @ sa_out_w^T + b -> bf16
  mk_mfma<<<dim3(192, 1), 256, 0, stream>>>(ctxa_b, saow_b, sa_out_b, ctx_b,
      768, 768, 768, 768, 1, 0, 0, 0, 0, 0, 0, 0, nullptr, 6,
      1, 1 << 30, nullptr, 0, 0, 0);
  // 6. q2 = ctx @ ca_in_w[:768]^T + b (fp32 out)
  mk_mfma<<<dim3(192, 1), 256, 0, stream>>>(ctx_b, caw_b, ca_in_b, q2,
      768, 768, 768, 768, 1, 0, 0, 0, 0, 0, 0, 0, nullptr, 6,
      0, 1 << 30, nullptr, 0, 0, 0);
  // 7. k2 = eq @ ca_in_w[768:]^T + b  (8x768x768 fp32)
  mk_gemm<<<dim3(12, 1), 256, 0, stream>>>(eq, ca_in_w + 589824, ca_in_b + 768, k2,
      8, 768, 768, 768, 768, 768, 12);
  // 8. gate
  (void)hipMemsetAsync(gacc, 0, 128 * sizeof(float), stream);
  (void)hipMemsetAsync(eo, 0, 24576 * sizeof(float), stream);
  mk_gates<<<256, 256, 0, stream>>>(q2, k2, gacc);
  mk_gatetop<<<1, 64, 0, stream>>>(gacc, pe, pw);
  // 9. xz = x @ e_in_w[e]^T + b (Z=32 pair mode) split -> xz_x | xz_z
  mk_mfma<<<dim3(24, 32), 256, 0, stream>>>(xb, ew_b, e_in_b, xz_x,
      768, 768, 768, 768, 1, 196608, 0, 1179648, 0, 196608, 0, 1536, pe, 12,
      0, 768, xz_z, 768, 0, 0);
  // 10. depthwise conv + SiLU
  mk_conv<<<32 * 256, 768, 0, stream>>>(xz_x, e_conv_w, e_conv_b, pe, xc);
  // 11. dbl projections -> per-dir pre-permuted dblm2 (xz_x region dead)
  mk_dbl<<<2048, 256, 0, stream>>>(xc, e_xproj, pe, dblm);
  // 12. fused segmented scan (imm-offset LDS reads, 4-step fenced chunks)
  mk_scan<<<1536, 512, 0, stream>>>(xc, dblm, e_dtw, e_dtb, e_Alog, e_D, pe, yac);
  // 13. LN + silu(z) + token mean (512 blocks, atomic into eo)
  mk_lnfin<<<512, 256, 0, stream>>>(yac, xz_z, e_lns, e_lnb, pe, eo);
  // 14. weighted top-2 combine (1/256 folded)
  mk_out<<<16, 768, 0, stream>>>(eo, pw, out);

  (void)in_sizes; (void)n_in; (void)out_size; (void)ws_size;
}

// Round 9
// 622.435 us; speedup vs baseline: 1.3617x; 1.0107x over previous
//
#include <hip/hip_runtime.h>
#include <hip/hip_bf16.h>

// MoEFSCIL: B=16, H=W=16, L=256, DIM=768, NH=8, HD=96, NEXP=8, TOPK=2.
// fp32 in/out. ALL GEMMs bf16 MFMA with global_load_lds(16B) direct-to-LDS
// staging + XOR-swizzled linear LDS (guide m93->m97 +69% lever; pre-swizzled
// global source per rule #21, read offset XOR'd, round-trip verified; bank
// spread == old padded layout). Scan kept at r7 state (155us floor: addr-VALU,
// conflicts, chain length, occupancy all proven non-binding over r3/r5/r7).
// r8 bench: container failed twice, no diagnostics -> static audit found no
// fault/hang path (uniform LDS base, lane*16B mapping exact, bounds/align OK,
// vmcnt drained by barriers); resubmitting with hardened intrinsic wrapper.
// Pre-committed: second double-failure => GLD16 incompatible with harness,
// r10 reverts staging only.

#define LTOK 256
#define DIMC 768

typedef unsigned short ushortt;
typedef __attribute__((ext_vector_type(8))) short bf16x8;
typedef __attribute__((ext_vector_type(4))) float f32x4;

#define LOG2E 1.44269504f
#define LN2   0.69314718f

__device__ __forceinline__ void gld16(const ushortt* gp, ushortt* lp) {
  __builtin_amdgcn_global_load_lds(
      (const __attribute__((address_space(1))) void*)gp,
      (__attribute__((address_space(3))) void*)lp, 16, 0, 0);
}

__device__ __forceinline__ float fexp2(float x) { return __builtin_amdgcn_exp2f(x); }
__device__ __forceinline__ float flog2(float x) { return __builtin_amdgcn_logf(x); }

__device__ __forceinline__ ushortt f2b(float f) {
  union { float f; unsigned u; } c; c.f = f;
  unsigned r = (c.u + 0x7FFFu + ((c.u >> 16) & 1u)) >> 16;
  return (ushortt)r;
}

// ---------------------------------------------------------------------------
// Fused 4-tensor fp32->bf16 cast (x, sa_in_w, sa_out_w, ca_in_w[:768] rows).
// ---------------------------------------------------------------------------
__global__ __launch_bounds__(256) void mk_mcast4(
    const float* __restrict__ s0, ushortt* __restrict__ d0,
    const float* __restrict__ s1, ushortt* __restrict__ d1,
    const float* __restrict__ s2, ushortt* __restrict__ d2,
    const float* __restrict__ s3, ushortt* __restrict__ d3)
{
  long g = (long)blockIdx.x * 256 + threadIdx.x;   // float4 chunk id
  const float* s; ushortt* dst; long o;
  if (g < 786432)       { s = s0; dst = d0; o = g; }
  else if (g < 1228800) { s = s1; dst = d1; o = g - 786432; }
  else if (g < 1376256) { s = s2; dst = d2; o = g - 1228800; }
  else                  { s = s3; dst = d3; o = g - 1376256; }
  o <<= 2;
  float4 v = *(const float4*)(s + o);
  ushort4 w;
  w.x = f2b(v.x); w.y = f2b(v.y); w.z = f2b(v.z); w.w = f2b(v.w);
  *(ushort4*)(dst + o) = w;
}

__global__ __launch_bounds__(256) void mk_cast(const float* __restrict__ in,
                                               ushortt* __restrict__ outp, long n)
{
  long i = ((long)blockIdx.x * 256 + threadIdx.x) * 4;
  if (i + 3 < n) {
    float4 v = *(const float4*)(in + i);
    ushort4 o;
    o.x = f2b(v.x); o.y = f2b(v.y); o.z = f2b(v.z); o.w = f2b(v.w);
    *(ushort4*)(outp + i) = o;
  }
}

// ---------------------------------------------------------------------------
// bf16 MFMA GEMM: C[z] = A[z](M,K) @ B[z](N,K)^T + bias.
// Staging: global_load_lds width=16, linear LDS [128][32] ushort with XOR
// swizzle phys_grp = log_grp ^ ((row>>1)&3):
//   write: lane l stages global grp (l&3)^((l>>3)&3) of row (l>>2) -> slot l
//          (byte offset (l>>2)*64 + (l&3)*16 = l*16 = HW lane mapping)
//   read : logical (row, lg) at phys grp lg ^ ((lm>>1)&3)
// Round-trip = identity; read bank spread = 8 lanes/quad (2-way, free).
// Batch: pairExp (MoE) or zdiv (z1=z/zdiv, z2=z%zdiv) offsets.
// Column split at splitN: cols<splitN -> C (outBf), else C2 (outBf2, ldc2).
// c2vt: C2 written in vt layout [(b*8+h)*128 + j][t] (qkv v-transpose).
// ---------------------------------------------------------------------------
__global__ __launch_bounds__(256) void mk_mfma(
    const ushortt* __restrict__ A, const ushortt* __restrict__ B,
    const float* __restrict__ bias, void* __restrict__ C,
    int K, int lda, int ldb, int ldc,
    int zdiv, long sA1, long sA2, long sB1, long sB2, long sC1, long sC2,
    long sBias,
    const int* __restrict__ pairExp, int tilesN,
    int outBf, int splitN, void* __restrict__ C2, int ldc2, int outBf2, int c2vt)
{
  int z = blockIdx.y;
  long aoff, boff, coff, biasoff = 0;
  if (pairExp) {
    int e = pairExp[z];
    aoff = (long)(z >> 1) * sA1; boff = (long)e * sB1;
    coff = (long)z * sC1; biasoff = (long)e * sBias;
  } else {
    int z1 = z / zdiv, z2 = z - z1 * zdiv;
    aoff = (long)z1 * sA1 + (long)z2 * sA2;
    boff = (long)z1 * sB1 + (long)z2 * sB2;
    coff = (long)z1 * sC1 + (long)z2 * sC2;
  }
  int tile = blockIdx.x;
  int tm = tile / tilesN, tn = tile - tm * tilesN;
  long m0 = (long)tm << 7, n0 = (long)tn << 7;

  __shared__ ushortt As[128 * 32];
  __shared__ ushortt Bs[128 * 32];

  int tid = threadIdx.x;
  int lane = tid & 63, wvi = tid >> 6;
  int wr = wvi >> 1, wc = wvi & 1;
  int lm = lane & 15, lg = lane >> 4;

  f32x4 zero4 = {0.f, 0.f, 0.f, 0.f};
  f32x4 acc[4][4];
#pragma unroll
  for (int i = 0; i < 4; i++)
#pragma unroll
    for (int j = 0; j < 4; j++) acc[i][j] = zero4;

  const ushortt* Ab = A + aoff;
  const ushortt* Bb = B + boff;

  // staging constants: lane l covers row (wvi*32 + l/4 [+16 for 2nd instr]),
  // fetches logical 16B-group (l&3)^((l>>3)&3) (pre-swizzled source).
  int srow = (wvi << 5) + (lane >> 2);
  int sglog = ((lane & 3) ^ ((lane >> 3) & 3)) << 3;   // ushort offset
  const ushortt* agp = Ab + (m0 + srow) * lda + sglog;
  const ushortt* bgp = Bb + (n0 + srow) * ldb + sglog;
  ushortt* al0 = &As[(wvi << 5) << 5];
  ushortt* al1 = &As[((wvi << 5) + 16) << 5];
  ushortt* bl0 = &Bs[(wvi << 5) << 5];
  ushortt* bl1 = &Bs[((wvi << 5) + 16) << 5];

  // fragment LDS addresses (loop-invariant): phys grp = lg ^ ((lm>>1)&3)
  int pswz = (lg ^ ((lm >> 1) & 3)) << 3;
  const ushortt* afp[4];
  const ushortt* bfp[4];
#pragma unroll
  for (int i = 0; i < 4; i++) {
    afp[i] = &As[((wr * 64 + i * 16 + lm) << 5) + pswz];
    bfp[i] = &Bs[((wc * 64 + i * 16 + lm) << 5) + pswz];
  }

  for (int k0 = 0; k0 < K; k0 += 32) {
    gld16(agp, al0);
    gld16(agp + 16 * lda, al1);
    gld16(bgp, bl0);
    gld16(bgp + 16 * ldb, bl1);
    agp += 32; bgp += 32;
    __syncthreads();
    bf16x8 af[4], bfr[4];
#pragma unroll
    for (int i = 0; i < 4; i++) {
      af[i] = *(const bf16x8*)afp[i];
      bfr[i] = *(const bf16x8*)bfp[i];
    }
#pragma unroll
    for (int i = 0; i < 4; i++)
#pragma unroll
      for (int j = 0; j < 4; j++)
        acc[i][j] = __builtin_amdgcn_mfma_f32_16x16x32_bf16(af[i], bfr[j], acc[i][j], 0, 0, 0);
    __syncthreads();
  }

#pragma unroll
  for (int mt = 0; mt < 4; mt++) {
#pragma unroll
    for (int nt = 0; nt < 4; nt++) {
      long grow = m0 + wr * 64 + mt * 16 + lg * 4;
      long gcol = n0 + wc * 64 + nt * 16 + lm;
      float bv = bias ? bias[biasoff + gcol] : 0.f;
      if ((int)gcol < splitN) {
#pragma unroll
        for (int r = 0; r < 4; r++) {
          float v = acc[mt][nt][r] + bv;
          long idx = coff + (grow + r) * ldc + gcol;
          if (outBf) ((ushortt*)C)[idx] = f2b(v);
          else ((float*)C)[idx] = v;
        }
      } else if (c2vt) {
        int cc = (int)gcol - splitN;            // 0..767
        int hh = cc / 96, jj = cc - hh * 96;
#pragma unroll
        for (int r = 0; r < 4; r++) {
          float v = acc[mt][nt][r] + bv;
          long gr = grow + r;
          long b = gr >> 8, t = gr & 255;
          long idx = (((b * 8 + hh) * 128 + jj) << 8) + t;
          ((ushortt*)C2)[idx] = f2b(v);
        }
      } else {
        long col = gcol - splitN;
#pragma unroll
        for (int r = 0; r < 4; r++) {
          float v = acc[mt][nt][r] + bv;
          long idx = coff + (grow + r) * ldc2 + col;
          if (outBf2) ((ushortt*)C2)[idx] = f2b(v);
          else ((float*)C2)[idx] = v;
        }
      }
    }
  }
}

// ---------------------------------------------------------------------------
// fp32 GEMM (k2 only now).
// ---------------------------------------------------------------------------
__global__ __launch_bounds__(256) void mk_gemm(
    const float* __restrict__ A, const float* __restrict__ B,
    const float* __restrict__ bias, float* __restrict__ C,
    int M, int N, int K, int lda, int ldb, int ldc, int tilesN)
{
  int tile = blockIdx.x;
  int tm = tile / tilesN, tn = tile - tm * tilesN;
  int m0 = tm << 6, n0 = tn << 6;

  __shared__ float As[16][68];
  __shared__ float Bs[16][68];

  int tid = threadIdx.x;
  int tx = tid & 15, ty = tid >> 4;
  int lrow = tid >> 2;
  int lk = (tid & 3) << 2;

  float acc[4][4];
#pragma unroll
  for (int i = 0; i < 4; i++)
#pragma unroll
    for (int j = 0; j < 4; j++) acc[i][j] = 0.f;

  for (int k0 = 0; k0 < K; k0 += 16) {
    {
      int gm = m0 + lrow;
      float4 v = {0.f, 0.f, 0.f, 0.f};
      if (gm < M) v = *(const float4*)(A + (long)gm * lda + (k0 + lk));
      As[lk + 0][lrow] = v.x; As[lk + 1][lrow] = v.y;
      As[lk + 2][lrow] = v.z; As[lk + 3][lrow] = v.w;
    }
    {
      int gn = n0 + lrow;
      float4 v = {0.f, 0.f, 0.f, 0.f};
      if (gn < N) v = *(const float4*)(B + (long)gn * ldb + (k0 + lk));
      Bs[lk + 0][lrow] = v.x; Bs[lk + 1][lrow] = v.y;
      Bs[lk + 2][lrow] = v.z; Bs[lk + 3][lrow] = v.w;
    }
    __syncthreads();
#pragma unroll
    for (int kk = 0; kk < 16; kk++) {
      float4 a = *(const float4*)&As[kk][ty << 2];
      float4 b = *(const float4*)&Bs[kk][tx << 2];
      acc[0][0] += a.x * b.x; acc[0][1] += a.x * b.y; acc[0][2] += a.x * b.z; acc[0][3] += a.x * b.w;
      acc[1][0] += a.y * b.x; acc[1][1] += a.y * b.y; acc[1][2] += a.y * b.z; acc[1][3] += a.y * b.w;
      acc[2][0] += a.z * b.x; acc[2][1] += a.z * b.y; acc[2][2] += a.z * b.z; acc[2][3] += a.z * b.w;
      acc[3][0] += a.w * b.x; acc[3][1] += a.w * b.y; acc[3][2] += a.w * b.z; acc[3][3] += a.w * b.w;
    }
    __syncthreads();
  }

#pragma unroll
  for (int i = 0; i < 4; i++) {
    int gm = m0 + (ty << 2) + i;
    if (gm >= M) continue;
#pragma unroll
    for (int j = 0; j < 4; j++) {
      int gn = n0 + (tx << 2) + j;
      if (gn >= N) continue;
      float v = acc[i][j];
      if (bias) v += bias[gn];
      C[(long)gm * ldc + gn] = v;
    }
  }
}

// ---------------------------------------------------------------------------
// Softmax: fp32 scores in, bf16 att out (scale folded).
// ---------------------------------------------------------------------------
__global__ __launch_bounds__(256) void mk_softmax(const float* __restrict__ scores,
                                                  ushortt* __restrict__ att, float scale)
{
  int row = (blockIdx.x << 2) + (threadIdx.x >> 6);
  int lane = threadIdx.x & 63;
  const float* p = scores + (long)row * 256 + (lane << 2);
  float4 v = *(const float4*)p;
  float m = fmaxf(fmaxf(v.x, v.y), fmaxf(v.z, v.w));
#pragma unroll
  for (int o = 32; o; o >>= 1) m = fmaxf(m, __shfl_xor(m, o, 64));
  float sl = scale * LOG2E;
  v.x = fexp2(sl * (v.x - m));
  v.y = fexp2(sl * (v.y - m));
  v.z = fexp2(sl * (v.z - m));
  v.w = fexp2(sl * (v.w - m));
  float s = v.x + v.y + v.z + v.w;
#pragma unroll
  for (int o = 32; o; o >>= 1) s += __shfl_xor(s, o, 64);
  float r = 1.f / s;
  ushort4 o4;
  o4.x = f2b(v.x * r); o4.y = f2b(v.y * r); o4.z = f2b(v.z * r); o4.w = f2b(v.w * r);
  *(ushort4*)(att + (long)row * 256 + (lane << 2)) = o4;
}

// ---------------------------------------------------------------------------
__global__ __launch_bounds__(256) void mk_gates(const float* __restrict__ q2,
                                                const float* __restrict__ k2,
                                                float* __restrict__ gacc)
{
  __shared__ float k2p[8 * 808];
  int b = blockIdx.x >> 4, q = blockIdx.x & 15;
  for (int i = threadIdx.x; i < 6144; i += 256) {
    int e = i / 768, rem = i - e * 768;
    int h = rem / 96, j = rem - h * 96;
    k2p[e * 808 + h * 100 + j] = k2[i];
  }
  __syncthreads();
  const float scale = 0.10206207261596577f;
  int wid = threadIdx.x >> 6, lane = threadIdx.x & 63;
  int h = lane >> 3, e = lane & 7;
  const float* kp = &k2p[e * 808 + h * 100];
  float accL = 0.f;
#pragma unroll
  for (int ti = 0; ti < 4; ti++) {
    int l = q * 16 + wid * 4 + ti;
    const float* qh = q2 + ((long)b * LTOK + l) * DIMC + h * 96;
    float sum = 0.f;
#pragma unroll
    for (int j = 0; j < 96; j += 4) {
      float4 qv = *(const float4*)(qh + j);
      float4 kv = *(const float4*)(kp + j);
      sum += qv.x * kv.x + qv.y * kv.y + qv.z * kv.z + qv.w * kv.w;
    }
    float s = sum * scale;
    float mx = s;
#pragma unroll
    for (int o = 1; o <= 4; o <<= 1) mx = fmaxf(mx, __shfl_xor(mx, o, 64));
    float ex = fexp2((s - mx) * LOG2E);
    float se = ex;
#pragma unroll
    for (int o = 1; o <= 4; o <<= 1) se += __shfl_xor(se, o, 64);
    accL += ex / se;
  }
#pragma unroll
  for (int o = 8; o <= 32; o <<= 1) accL += __shfl_xor(accL, o, 64);
  __shared__ float red[4][8];
  if (lane < 8) red[wid][lane] = accL;
  __syncthreads();
  if (threadIdx.x < 8) {
    float v = red[0][threadIdx.x] + red[1][threadIdx.x] +
              red[2][threadIdx.x] + red[3][threadIdx.x];
    atomicAdd(&gacc[b * 8 + threadIdx.x], v);
  }
}

__global__ __launch_bounds__(64) void mk_gatetop(const float* __restrict__ gacc,
                                                 int* __restrict__ pe,
                                                 float* __restrict__ pw)
{
  int b = threadIdx.x;
  if (b >= 16) return;
  float g[8];
  for (int e = 0; e < 8; e++) g[e] = gacc[b * 8 + e] * (1.f / (8.f * 256.f));
  float mx = g[0];
  for (int e = 1; e < 8; e++) mx = fmaxf(mx, g[e]);
  float se = 0.f;
  for (int e = 0; e < 8; e++) { g[e] = expf(g[e] - mx); se += g[e]; }
  for (int e = 0; e < 8; e++) g[e] /= se;
  int i0 = 0;
  for (int e = 1; e < 8; e++) if (g[e] > g[i0]) i0 = e;
  int i1 = (i0 == 0) ? 1 : 0;
  for (int e = 0; e < 8; e++) if (e != i0 && g[e] > g[i1]) i1 = e;
  float w0 = 1.f / (1.f + expf(g[i1] - g[i0]));
  pe[2 * b] = i0; pe[2 * b + 1] = i1;
  pw[2 * b] = w0; pw[2 * b + 1] = 1.f - w0;
}

// ---------------------------------------------------------------------------
__global__ __launch_bounds__(768) void mk_conv(const float* __restrict__ xzx,
                                               const float* __restrict__ cw,
                                               const float* __restrict__ cb,
                                               const int* __restrict__ pe,
                                               float* __restrict__ xc)
{
  int blk = blockIdx.x;
  int p = blk >> 8, t = blk & 255;
  int e = pe[p];
  int h = t >> 4, w = t & 15;
  int c = threadIdx.x;
  const float* wp = cw + ((long)e * DIMC + c) * 9;
  float acc = cb[e * DIMC + c];
#pragma unroll
  for (int dh = 0; dh < 3; dh++) {
    int hh = h + dh - 1;
    if (hh < 0 || hh > 15) continue;
#pragma unroll
    for (int dw = 0; dw < 3; dw++) {
      int ww = w + dw - 1;
      if (ww < 0 || ww > 15) continue;
      acc += xzx[((long)p * LTOK + hh * 16 + ww) * DIMC + c] * wp[dh * 3 + dw];
    }
  }
  xc[((long)p * LTOK + t) * DIMC + c] = acc / (1.f + fexp2(-acc * LOG2E));
}

__device__ __forceinline__ int tmap(int dir, int s) {
  if (dir == 0) return s;
  if (dir == 1) return 255 - s;
  if (dir == 2) return ((s & 15) << 4) | (s >> 4);
  int u = 255 - s;
  return ((u & 15) << 4) | (u >> 4);
}

// ---------------------------------------------------------------------------
// dbl: wave-per-token, lanes on channel dim (coalesced). Output dblm2[p]:
// PER-DIR TRAVERSAL ORDER, bank-staggered: position s = tmap(dir, m)
// (involution), ss = (s&31)*8 + (s>>5).
//   dt image : dblm2[p*6144 + dir*1024 + ss*4 + 0..3]   (16B rows)
//   BC image : dblm2[p*6144 + 4096 + dir*512 + ss*2 + 0..1] (8B rows)
// ---------------------------------------------------------------------------
__global__ __launch_bounds__(256) void mk_dbl(const float* __restrict__ xc,
                                              const float* __restrict__ xproj,
                                              const int* __restrict__ pe,
                                              float* __restrict__ dblm)
{
  int p = blockIdx.x >> 6;
  int tq = blockIdx.x & 63;
  int wid = threadIdx.x >> 6, lane = threadIdx.x & 63;
  int m = tq * 4 + wid;
  int e = pe[p];
  const float* xr = xc + ((long)p * LTOK + m) * DIMC;
  const float* wb = xproj + (long)e * 24 * DIMC;
  float4 xv[3];
#pragma unroll
  for (int j = 0; j < 3; j++) xv[j] = *(const float4*)(xr + j * 256 + lane * 4);
  float acc[24];
#pragma unroll
  for (int r = 0; r < 24; r++) {
    const float* wr = wb + r * DIMC;
    float s = 0.f;
#pragma unroll
    for (int j = 0; j < 3; j++) {
      float4 wv = *(const float4*)(wr + j * 256 + lane * 4);
      s += xv[j].x * wv.x + xv[j].y * wv.y + xv[j].z * wv.z + xv[j].w * wv.w;
    }
    acc[r] = s;
  }
#pragma unroll
  for (int r = 0; r < 24; r++)
#pragma unroll
    for (int o = 32; o; o >>= 1) acc[r] += __shfl_xor(acc[r], o, 64);
  if (lane == 0) {
    float* o = dblm + (long)p * 6144;
#pragma unroll
    for (int dd = 0; dd < 4; dd++) {
      int s = tmap(dd, m);
      int ss = ((s & 31) << 3) | (s >> 5);
      float* oa = o + dd * 1024 + ss * 4;
      oa[0] = acc[dd * 6 + 0]; oa[1] = acc[dd * 6 + 1];
      oa[2] = acc[dd * 6 + 2]; oa[3] = acc[dd * 6 + 3];
      float* ob = o + 4096 + dd * 512 + ss * 2;
      ob[0] = acc[dd * 6 + 4]; ob[1] = acc[dd * 6 + 5];
    }
  }
}

// ---------------------------------------------------------------------------
// Fused segmented scan, two-pass recompute, pre-permuted operands, FENCED:
//  512 thr = 16c x 8seg x 4dir; 32 steps/segment in 4-step chunks; each chunk
//  ends with sched_barrier(0) (r6 lesson: unfenced imm-offset loads hoist ->
//  ~190-float live window -> 1GB scratch). Per step: ds_read_b128 (dt) +
//  ds_read_b64 (B/C) at base+imm, conflict-free.
//  LDS = 16K dtS + 8K bcS + 18K yS + 4K ahS + 64B = 47.4 KB -> 3 blocks/CU.
// ---------------------------------------------------------------------------
__global__ __launch_bounds__(512, 6) void mk_scan(const float* __restrict__ xc,
                                               const float* __restrict__ dblm,
                                               const float* __restrict__ dtw,
                                               const float* __restrict__ dtb,
                                               const float* __restrict__ Alog,
                                               const float* __restrict__ Dp,
                                               const int* __restrict__ pe,
                                               float* __restrict__ yac)
{
  __shared__ __attribute__((aligned(16))) float dtS[4096];   // [dir][ss][4]
  __shared__ __attribute__((aligned(16))) float bcS[2048];   // [dir][ss][2]
  __shared__ float yS[256 * 18];
  __shared__ float ahS[32][16][2];
  __shared__ float dsum[16];
  int blk = blockIdx.x;
  int p = blk / 48, cg = blk - p * 48;
  int c0 = cg << 4;
  int e = pe[p];
  int tid = threadIdx.x;
  // stage dblm2[p]: contiguous 24KB copy (already permuted + staggered)
  {
    const float4* src = (const float4*)(dblm + (long)p * 6144);
    float4* dA = (float4*)dtS;
    for (int i = tid; i < 1024; i += 512) dA[i] = src[i];
    if (tid < 512) ((float4*)bcS)[tid] = src[1024 + tid];
  }
  for (int i = tid; i < 256 * 18; i += 512) yS[i] = 0.f;
  if (tid < 16) {
    float s = 0.f;
#pragma unroll
    for (int dd = 0; dd < 4; dd++) s += Dp[(long)(e * 4 + dd) * DIMC + c0 + tid];
    dsum[tid] = s;
  }
  __syncthreads();

  int c = tid & 15;
  int rr = tid >> 4;
  int seg = rr & 7;
  int dir = rr >> 3;
  int d = c0 + c;
  const float* xcp = xc + (long)p * LTOK * DIMC + d;
  long pb = (long)(e * 4 + dir) * DIMC + d;
  float4 wv = *(const float4*)(dtw + pb * 4);
  wv.x *= LOG2E; wv.y *= LOG2E; wv.z *= LOG2E; wv.w *= LOG2E;
  float bdt = dtb[pb] * LOG2E;
  float Ad = -fexp2(Alog[pb] * LOG2E);
  int t0 = seg << 5;
  const float* dtP = &dtS[(dir << 10) + (seg << 2)];
  const float* bcP = &bcS[(dir << 9) + (seg << 1)];

  // pass 1: per-segment (ap, h) only; 4-step fenced chunks
  float h = 0.f, ap = 1.f;
#pragma unroll 1
  for (int tb = 0; tb < 32; tb += 4) {
#pragma unroll
    for (int u = 0; u < 4; u++) {
      int i = tb + u;
      float4 dv = *(const float4*)(dtP + i * 32);
      float2 bc = *(const float2*)(bcP + i * 16);
      int mm = tmap(dir, t0 + i);
      float xv = xcp[(long)mm * DIMC];
      float xl = wv.x * dv.x + wv.y * dv.y + wv.z * dv.z + wv.w * dv.w + bdt;
      float te = fexp2(xl);
      float g = flog2(1.f + te);
      g = (xl > 86.f) ? xl : g;
      float de = fexp2(g * Ad);
      h = de * h + (g * LN2 * bc.x) * xv;
      ap *= de;
    }
    __builtin_amdgcn_sched_barrier(0);
  }
  ahS[rr][c][0] = ap;
  ahS[rr][c][1] = h;
  __syncthreads();

  // batched segment combine
  float hh = 0.f;
  {
    int base = dir << 3;
    float av[8], hv[8];
#pragma unroll
    for (int j = 0; j < 8; j++) {
      av[j] = ahS[base + j][c][0];
      hv[j] = ahS[base + j][c][1];
    }
#pragma unroll
    for (int j = 0; j < 7; j++)
      if (j < seg) hh = av[j] * hh + hv[j];
  }

  // pass 2: recompute with carried state, emit C*h atomics; fenced chunks
#pragma unroll 1
  for (int tb = 0; tb < 32; tb += 4) {
#pragma unroll
    for (int u = 0; u < 4; u++) {
      int i = tb + u;
      float4 dv = *(const float4*)(dtP + i * 32);
      float2 bc = *(const float2*)(bcP + i * 16);
      int mm = tmap(dir, t0 + i);
      float xv = xcp[(long)mm * DIMC];
      float xl = wv.x * dv.x + wv.y * dv.y + wv.z * dv.z + wv.w * dv.w + bdt;
      float te = fexp2(xl);
      float g = flog2(1.f + te);
      g = (xl > 86.f) ? xl : g;
      float de = fexp2(g * Ad);
      hh = de * hh + (g * LN2 * bc.x) * xv;
      atomicAdd(&yS[mm * 18 + c + (((mm >> 5) & 1) << 1)], hh * bc.y);
    }
    __builtin_amdgcn_sched_barrier(0);
  }
  __syncthreads();

  const float* xcb = xc + (long)p * LTOK * DIMC + c0;
  float* yp = yac + (long)p * LTOK * DIMC + c0;
  for (int i = tid; i < 4096; i += 512) {
    int t = i >> 4, cz = i & 15;
    yp[(long)t * DIMC + cz] = yS[t * 18 + cz + (((t >> 5) & 1) << 1)] +
        xcb[(long)t * DIMC + cz] * dsum[cz];
  }
}

// ---------------------------------------------------------------------------
// LN + silu(z) + token partial-mean. 512 blocks = (p, 16-token slice).
// Accumulates into pre-zeroed eo via global atomics; 1/256 applied in mk_out.
// ---------------------------------------------------------------------------
__global__ __launch_bounds__(256) void mk_lnfin(const float* __restrict__ yac,
                                                const float* __restrict__ xzz,
                                                const float* __restrict__ lns,
                                                const float* __restrict__ lnb,
                                                const int* __restrict__ pe,
                                                float* __restrict__ eo)
{
  int blk = blockIdx.x;
  int p = blk >> 4, ts = blk & 15;
  int e = pe[p];
  int tid = threadIdx.x;
  int wid = tid >> 6, lane = tid & 63;
  float ls[12], lb[12], acc[12];
#pragma unroll
  for (int i = 0; i < 12; i++) {
    int d = i * 64 + lane;
    ls[i] = lns[e * DIMC + d];
    lb[i] = lnb[e * DIMC + d];
    acc[i] = 0.f;
  }
#pragma unroll
  for (int tt = 0; tt < 4; tt++) {
    int t = ts * 16 + wid * 4 + tt;
    const float* yr = yac + ((long)p * LTOK + t) * DIMC;
    const float* zr = xzz + ((long)p * LTOK + t) * DIMC;
    float v[12];
    float s = 0.f;
#pragma unroll
    for (int i = 0; i < 12; i++) { v[i] = yr[i * 64 + lane]; s += v[i]; }
#pragma unroll
    for (int o = 32; o; o >>= 1) s += __shfl_xor(s, o, 64);
    float mu = s * (1.f / 768.f);
    float sq = 0.f;
#pragma unroll
    for (int i = 0; i < 12; i++) { float dlt = v[i] - mu; sq += dlt * dlt; }
#pragma unroll
    for (int o = 32; o; o >>= 1) sq += __shfl_xor(sq, o, 64);
    float rs = rsqrtf(sq * (1.f / 768.f) + 1e-5f);
#pragma unroll
    for (int i = 0; i < 12; i++) {
      float y = (v[i] - mu) * rs * ls[i] + lb[i];
      float z = zr[i * 64 + lane];
      y *= z / (1.f + fexp2(-z * LOG2E));
      acc[i] += y;
    }
  }
  __shared__ float sacc[768];
  for (int j = tid; j < 768; j += 256) sacc[j] = 0.f;
  __syncthreads();
#pragma unroll
  for (int i = 0; i < 12; i++) atomicAdd(&sacc[i * 64 + lane], acc[i]);
  __syncthreads();
  for (int j = tid; j < 768; j += 256) atomicAdd(&eo[(long)p * DIMC + j], sacc[j]);
}

__global__ __launch_bounds__(768) void mk_out(const float* __restrict__ eo,
                                              const float* __restrict__ pw,
                                              float* __restrict__ out)
{
  int b = blockIdx.x, d = threadIdx.x;
  float v = pw[2 * b] * eo[(long)(2 * b) * DIMC + d] +
            pw[2 * b + 1] * eo[(long)(2 * b + 1) * DIMC + d];
  out[b * DIMC + d] = v * (1.f / 256.f);
}

// ---------------------------------------------------------------------------
extern "C" void kernel_launch(void* const* d_in, const int* in_sizes, int n_in,
                              void* d_out, int out_size, void* d_ws, size_t ws_size,
                              hipStream_t stream)
{
  const float* x        = (const float*)d_in[0];
  const float* sa_in_w  = (const float*)d_in[1];
  const float* sa_in_b  = (const float*)d_in[2];
  const float* sa_out_w = (const float*)d_in[3];
  const float* sa_out_b = (const float*)d_in[4];
  const float* ca_in_w  = (const float*)d_in[5];
  const float* ca_in_b  = (const float*)d_in[6];
  const float* eq       = (const float*)d_in[7];
  const float* e_in_w   = (const float*)d_in[8];
  const float* e_in_b   = (const float*)d_in[9];
  const float* e_conv_w = (const float*)d_in[10];
  const float* e_conv_b = (const float*)d_in[11];
  const float* e_xproj  = (const float*)d_in[12];
  const float* e_dtw    = (const float*)d_in[13];
  const float* e_dtb    = (const float*)d_in[14];
  const float* e_Alog   = (const float*)d_in[15];
  const float* e_D      = (const float*)d_in[16];
  const float* e_lns    = (const float*)d_in[17];
  const float* e_lnb    = (const float*)d_in[18];
  float* out = (float*)d_out;

  float* ws = (float*)d_ws;
  // ---- attention phase (float offsets) ----
  ushortt* qk_b   = (ushortt*)(ws + 0);          // 4096x1536 bf16  [0 .. 3,145,728)
  float*   scores = ws + 6291456;                // [6,291,456 .. 14,680,064)
  ushortt* dump_b = (ushortt*)(ws + 6291456);    // av dump (scores dead by then)
  ushortt* ctxa_b = (ushortt*)(ws + 7864320);    // 4096x768 bf16 [.. 9,437,184)
  ushortt* att_b  = (ushortt*)(ws + 14680064);   // 16x8x256x256 bf16 [.. 18,874,368)
  ushortt* vt_b   = (ushortt*)(ws + 18874368);   // 128x128x256 bf16 [.. 20,971,520)
  ushortt* xb     = (ushortt*)(ws + 20971520);   // [.. 22,544,384)
  ushortt* wqkv_b = (ushortt*)(ws + 22544384);   // [.. 23,429,120)
  ushortt* saow_b = (ushortt*)(ws + 23429120);   // [.. 23,724,032)
  ushortt* caw_b  = (ushortt*)(ws + 23724032);   // [.. 24,018,944)
  ushortt* ctx_b  = (ushortt*)(ws + 0);          // overlay qk_b (dead post-scores)
  float*   q2     = ws + 1572864;                // [.. 4,718,592) (qk_b dead)
  // ---- persistent smalls ----
  float*   k2     = ws + 25165824;
  int*     pe     = (int*)(ws + 25171968);
  float*   pw     = ws + 25172000;
  float*   eo     = ws + 25172032;               // [.. 25,196,608)
  float*   gacc   = ws + 25393216;               // [.. 25,393,344) peak 101.6MB
  // ---- expert phase ----
  float*   xz_x   = ws + 0;                      // [.. 6,291,456)
  float*   xz_z   = ws + 6291456;                // [.. 12,582,912) live -> lnfin
  ushortt* ew_b   = (ushortt*)(ws + 12582912);   // [.. 17,301,504) (scores/att dead)
  float*   xc     = ws + 12582912;               // [.. 18,874,368) after ew_b dead
  float*   yac    = ws + 18874368;               // [.. 25,165,824)
  float*   dblm   = ws + 0;                      // 32x6144 [.. 196,608) xz_x dead post-conv

  const float scale = 0.10206207261596577f;

  // 0. fused upfront casts: x, sa_in_w, sa_out_w, ca_in_w[:768]
  mk_mcast4<<<5952, 256, 0, stream>>>(x, xb, sa_in_w, wqkv_b, sa_out_w, saow_b,
                                      ca_in_w, caw_b);
  // 1. qkv MFMA: q,k -> qk_b bf16 (ld 1536); v -> vt_b transposed bf16
  mk_mfma<<<dim3(576, 1), 256, 0, stream>>>(xb, wqkv_b, sa_in_b, qk_b,
      768, 768, 768, 1536, 1, 0, 0, 0, 0, 0, 0, 0, nullptr, 18,
      1, 1536, vt_b, 0, 1, 1);
  // 2. scores = q @ k^T  (bf16 MFMA, K=96, Z=128, fp32 out)
  mk_mfma<<<dim3(4, 128), 256, 0, stream>>>(qk_b, qk_b + 768, nullptr, scores,
      96, 1536, 1536, 256, 8, 393216, 96, 393216, 96, 524288, 65536, 0, nullptr, 2,
      0, 1 << 30, nullptr, 0, 0, 0);
  // 3. softmax -> att_b bf16
  mk_softmax<<<8192, 256, 0, stream>>>(scores, att_b, scale);
  // 4. ctxa = att @ v  (bf16 MFMA via vt, N=96 + dump, Z=128)
  mk_mfma<<<dim3(2, 128), 256, 0, stream>>>(att_b, vt_b, nullptr, ctxa_b,
      256, 256, 256, 768, 8, 524288, 65536, 262144, 32768, 196608, 96, 0, nullptr, 1,
      1, 96, dump_b, 32, 1, 0);
  // 4b. cast expert weights (scores/att regions dead)
  mk_cast<<<9216, 256, 0, stream>>>(e_in_w, ew_b, 9437184);
  // 5. ctx = ctxa @ sa_out_w^T + b -> bf16
  mk_mfma<<<dim3(192, 1), 256, 0, stream>>>(ctxa_b, saow_b, sa_out_b, ctx_b,
      768, 768, 768, 768, 1, 0, 0, 0, 0, 0, 0, 0, nullptr, 6,
      1, 1 << 30, nullptr, 0, 0, 0);
  // 6. q2 = ctx @ ca_in_w[:768]^T + b (fp32 out)
  mk_mfma<<<dim3(192, 1), 256, 0, stream>>>(ctx_b, caw_b, ca_in_b, q2,
      768, 768, 768, 768, 1, 0, 0, 0, 0, 0, 0, 0, nullptr, 6,
      0, 1 << 30, nullptr, 0, 0, 0);
  // 7. k2 = eq @ ca_in_w[768:]^T + b  (8x768x768 fp32)
  mk_gemm<<<dim3(12, 1), 256, 0, stream>>>(eq, ca_in_w + 589824, ca_in_b + 768, k2,
      8, 768, 768, 768, 768, 768, 12);
  // 8. gate
  (void)hipMemsetAsync(gacc, 0, 128 * sizeof(float), stream);
  (void)hipMemsetAsync(eo, 0, 24576 * sizeof(float), stream);
  mk_gates<<<256, 256, 0, stream>>>(q2, k2, gacc);
  mk_gatetop<<<1, 64, 0, stream>>>(gacc, pe, pw);
  // 9. xz = x @ e_in_w[e]^T + b (Z=32 pair mode) split -> xz_x | xz_z
  mk_mfma<<<dim3(24, 32), 256, 0, stream>>>(xb, ew_b, e_in_b, xz_x,
      768, 768, 768, 768, 1, 196608, 0, 1179648, 0, 196608, 0, 1536, pe, 12,
      0, 768, xz_z, 768, 0, 0);
  // 10. depthwise conv + SiLU
  mk_conv<<<32 * 256, 768, 0, stream>>>(xz_x, e_conv_w, e_conv_b, pe, xc);
  // 11. dbl projections -> per-dir pre-permuted dblm2 (xz_x region dead)
  mk_dbl<<<2048, 256, 0, stream>>>(xc, e_xproj, pe, dblm);
  // 12. fused segmented scan (imm-offset LDS reads, 4-step fenced chunks)
  mk_scan<<<1536, 512, 0, stream>>>(xc, dblm, e_dtw, e_dtb, e_Alog, e_D, pe, yac);
  // 13. LN + silu(z) + token mean (512 blocks, atomic into eo)
  mk_lnfin<<<512, 256, 0, stream>>>(yac, xz_z, e_lns, e_lnb, pe, eo);
  // 14. weighted top-2 combine (1/256 folded)
  mk_out<<<16, 768, 0, stream>>>(eo, pw, out);

  (void)in_sizes; (void)n_in; (void)out_size; (void)ws_size;
}

// Round 11
// 580.079 us; speedup vs baseline: 1.4611x; 1.0730x over previous
//
#include <hip/hip_runtime.h>
#include <hip/hip_bf16.h>

// MoEFSCIL: B=16, H=W=16, L=256, DIM=768, NH=8, HD=96, NEXP=8, TOPK=2.
// fp32 in/out. ALL GEMMs bf16 MFMA with global_load_lds(16B) staging (r9,
// verified). Scan at r7 state (155us structural floor). r11 = r10 basket
// (softmax+attV fused, conv 8tok/block, memsets folded) with the r10 BUG
// FIXED: mk_cast (ew_b over [12.58M,17.30M) floats) ran between mk_attv and
// the ctx GEMM, clobbering ctxa at [14.68M,16.25M) -> gate path corrupted
// (absmax 0.19). Fix: mk_cast moved AFTER step 5 (single stream = strictly
// sequential; early placement bought nothing). ctxa/scores/vt all dead there.

#define LTOK 256
#define DIMC 768

typedef unsigned short ushortt;
typedef __attribute__((ext_vector_type(8))) short bf16x8;
typedef __attribute__((ext_vector_type(4))) float f32x4;

#define LOG2E 1.44269504f
#define LN2   0.69314718f

__device__ __forceinline__ void gld16(const ushortt* gp, ushortt* lp) {
  __builtin_amdgcn_global_load_lds(
      (const __attribute__((address_space(1))) void*)gp,
      (__attribute__((address_space(3))) void*)lp, 16, 0, 0);
}

__device__ __forceinline__ float fexp2(float x) { return __builtin_amdgcn_exp2f(x); }
__device__ __forceinline__ float flog2(float x) { return __builtin_amdgcn_logf(x); }

__device__ __forceinline__ ushortt f2b(float f) {
  union { float f; unsigned u; } c; c.f = f;
  unsigned r = (c.u + 0x7FFFu + ((c.u >> 16) & 1u)) >> 16;
  return (ushortt)r;
}

// ---------------------------------------------------------------------------
// Fused 4-tensor fp32->bf16 cast + gacc zero (block 0).
// ---------------------------------------------------------------------------
__global__ __launch_bounds__(256) void mk_mcast4(
    const float* __restrict__ s0, ushortt* __restrict__ d0,
    const float* __restrict__ s1, ushortt* __restrict__ d1,
    const float* __restrict__ s2, ushortt* __restrict__ d2,
    const float* __restrict__ s3, ushortt* __restrict__ d3,
    float* __restrict__ gacc)
{
  if (blockIdx.x == 0 && threadIdx.x < 128) gacc[threadIdx.x] = 0.f;
  long g = (long)blockIdx.x * 256 + threadIdx.x;   // float4 chunk id
  const float* s; ushortt* dst; long o;
  if (g < 786432)       { s = s0; dst = d0; o = g; }
  else if (g < 1228800) { s = s1; dst = d1; o = g - 786432; }
  else if (g < 1376256) { s = s2; dst = d2; o = g - 1228800; }
  else                  { s = s3; dst = d3; o = g - 1376256; }
  o <<= 2;
  float4 v = *(const float4*)(s + o);
  ushort4 w;
  w.x = f2b(v.x); w.y = f2b(v.y); w.z = f2b(v.z); w.w = f2b(v.w);
  *(ushort4*)(dst + o) = w;
}

__global__ __launch_bounds__(256) void mk_cast(const float* __restrict__ in,
                                               ushortt* __restrict__ outp, long n)
{
  long i = ((long)blockIdx.x * 256 + threadIdx.x) * 4;
  if (i + 3 < n) {
    float4 v = *(const float4*)(in + i);
    ushort4 o;
    o.x = f2b(v.x); o.y = f2b(v.y); o.z = f2b(v.z); o.w = f2b(v.w);
    *(ushort4*)(outp + i) = o;
  }
}

// ---------------------------------------------------------------------------
// bf16 MFMA GEMM: C[z] = A[z](M,K) @ B[z](N,K)^T + bias.
// Staging: global_load_lds width=16, linear LDS [128][32] ushort with XOR
// swizzle phys_grp = log_grp ^ ((row>>1)&3) (r9, verified).
// ---------------------------------------------------------------------------
__global__ __launch_bounds__(256) void mk_mfma(
    const ushortt* __restrict__ A, const ushortt* __restrict__ B,
    const float* __restrict__ bias, void* __restrict__ C,
    int K, int lda, int ldb, int ldc,
    int zdiv, long sA1, long sA2, long sB1, long sB2, long sC1, long sC2,
    long sBias,
    const int* __restrict__ pairExp, int tilesN,
    int outBf, int splitN, void* __restrict__ C2, int ldc2, int outBf2, int c2vt)
{
  int z = blockIdx.y;
  long aoff, boff, coff, biasoff = 0;
  if (pairExp) {
    int e = pairExp[z];
    aoff = (long)(z >> 1) * sA1; boff = (long)e * sB1;
    coff = (long)z * sC1; biasoff = (long)e * sBias;
  } else {
    int z1 = z / zdiv, z2 = z - z1 * zdiv;
    aoff = (long)z1 * sA1 + (long)z2 * sA2;
    boff = (long)z1 * sB1 + (long)z2 * sB2;
    coff = (long)z1 * sC1 + (long)z2 * sC2;
  }
  int tile = blockIdx.x;
  int tm = tile / tilesN, tn = tile - tm * tilesN;
  long m0 = (long)tm << 7, n0 = (long)tn << 7;

  __shared__ ushortt As[128 * 32];
  __shared__ ushortt Bs[128 * 32];

  int tid = threadIdx.x;
  int lane = tid & 63, wvi = tid >> 6;
  int wr = wvi >> 1, wc = wvi & 1;
  int lm = lane & 15, lg = lane >> 4;

  f32x4 zero4 = {0.f, 0.f, 0.f, 0.f};
  f32x4 acc[4][4];
#pragma unroll
  for (int i = 0; i < 4; i++)
#pragma unroll
    for (int j = 0; j < 4; j++) acc[i][j] = zero4;

  const ushortt* Ab = A + aoff;
  const ushortt* Bb = B + boff;

  int srow = (wvi << 5) + (lane >> 2);
  int sglog = ((lane & 3) ^ ((lane >> 3) & 3)) << 3;   // ushort offset
  const ushortt* agp = Ab + (m0 + srow) * lda + sglog;
  const ushortt* bgp = Bb + (n0 + srow) * ldb + sglog;
  ushortt* al0 = &As[(wvi << 5) << 5];
  ushortt* al1 = &As[((wvi << 5) + 16) << 5];
  ushortt* bl0 = &Bs[(wvi << 5) << 5];
  ushortt* bl1 = &Bs[((wvi << 5) + 16) << 5];

  int pswz = (lg ^ ((lm >> 1) & 3)) << 3;
  const ushortt* afp[4];
  const ushortt* bfp[4];
#pragma unroll
  for (int i = 0; i < 4; i++) {
    afp[i] = &As[((wr * 64 + i * 16 + lm) << 5) + pswz];
    bfp[i] = &Bs[((wc * 64 + i * 16 + lm) << 5) + pswz];
  }

  for (int k0 = 0; k0 < K; k0 += 32) {
    gld16(agp, al0);
    gld16(agp + 16 * lda, al1);
    gld16(bgp, bl0);
    gld16(bgp + 16 * ldb, bl1);
    agp += 32; bgp += 32;
    __syncthreads();
    bf16x8 af[4], bfr[4];
#pragma unroll
    for (int i = 0; i < 4; i++) {
      af[i] = *(const bf16x8*)afp[i];
      bfr[i] = *(const bf16x8*)bfp[i];
    }
#pragma unroll
    for (int i = 0; i < 4; i++)
#pragma unroll
      for (int j = 0; j < 4; j++)
        acc[i][j] = __builtin_amdgcn_mfma_f32_16x16x32_bf16(af[i], bfr[j], acc[i][j], 0, 0, 0);
    __syncthreads();
  }

#pragma unroll
  for (int mt = 0; mt < 4; mt++) {
#pragma unroll
    for (int nt = 0; nt < 4; nt++) {
      long grow = m0 + wr * 64 + mt * 16 + lg * 4;
      long gcol = n0 + wc * 64 + nt * 16 + lm;
      float bv = bias ? bias[biasoff + gcol] : 0.f;
      if ((int)gcol < splitN) {
#pragma unroll
        for (int r = 0; r < 4; r++) {
          float v = acc[mt][nt][r] + bv;
          long idx = coff + (grow + r) * ldc + gcol;
          if (outBf) ((ushortt*)C)[idx] = f2b(v);
          else ((float*)C)[idx] = v;
        }
      } else if (c2vt) {
        int cc = (int)gcol - splitN;            // 0..767
        int hh = cc / 96, jj = cc - hh * 96;
#pragma unroll
        for (int r = 0; r < 4; r++) {
          float v = acc[mt][nt][r] + bv;
          long gr = grow + r;
          long b = gr >> 8, t = gr & 255;
          long idx = (((b * 8 + hh) * 128 + jj) << 8) + t;
          ((ushortt*)C2)[idx] = f2b(v);
        }
      } else {
        long col = gcol - splitN;
#pragma unroll
        for (int r = 0; r < 4; r++) {
          float v = acc[mt][nt][r] + bv;
          long idx = coff + (grow + r) * ldc2 + col;
          if (outBf2) ((ushortt*)C2)[idx] = f2b(v);
          else ((float*)C2)[idx] = v;
        }
      }
    }
  }
}

// ---------------------------------------------------------------------------
// Fused softmax + att@V: block = (half, z). z = b*8+h. Rows = half*128+0..127.
//  pre-pass: 2 threads/row compute rowmax m + rinv=1/sum(exp2(sl*(s-m)))
//  (bitwise-identical ops to old mk_softmax). V (96x256 bf16 vt layout)
//  staged once (Vs[96][264]); K-loop stages P-tiles on the fly; 4 waves x
//  (2m x 6n) MFMA. Epilogue -> ctxa bf16. Replaces 2 dispatches + att_b
//  round-trip + the 32 dump columns.
// ---------------------------------------------------------------------------
__global__ __launch_bounds__(256) void mk_attv(const float* __restrict__ scores,
                                               const ushortt* __restrict__ vt,
                                               ushortt* __restrict__ ctxa)
{
  __shared__ ushortt Vs[96 * 264];
  __shared__ __attribute__((aligned(16))) ushortt As[128 * 40];
  int z = blockIdx.y, half = blockIdx.x;
  int t = threadIdx.x;
  const float* srow = scores + (long)z * 65536 + (long)half * 128 * 256;
  const ushortt* vb = vt + (long)z * 32768;

  // stage V: 96 rows x 256 cols -> stride 264
  for (int it = 0; it < 12; it++) {
    int cch = it * 256 + t;            // 0..3071 uint4 chunks
    int j = cch >> 5, q = cch & 31;
    *(uint4*)&Vs[j * 264 + q * 8] = *(const uint4*)(vb + j * 256 + q * 8);
  }

  // pre-pass: row r = t>>1, half-row hf = t&1 (adjacent lanes pair via shfl)
  int r = t >> 1, hf = t & 1;
  const float* sp = srow + (long)r * 256 + hf * 128;
  const float sl = 0.10206207261596577f * LOG2E;
  float m = -3.4e38f;
  for (int j = 0; j < 128; j += 4) {
    float4 v = *(const float4*)(sp + j);
    m = fmaxf(m, fmaxf(fmaxf(v.x, v.y), fmaxf(v.z, v.w)));
  }
  m = fmaxf(m, __shfl_xor(m, 1, 64));
  float s = 0.f;
  for (int j = 0; j < 128; j += 4) {
    float4 v = *(const float4*)(sp + j);
    s += fexp2(sl * (v.x - m)) + fexp2(sl * (v.y - m)) +
         fexp2(sl * (v.z - m)) + fexp2(sl * (v.w - m));
  }
  s += __shfl_xor(s, 1, 64);
  float rinv = 1.f / s;

  int lane = t & 63, w = t >> 6;
  int lm = lane & 15, lg = lane >> 4;
  f32x4 zero4 = {0.f, 0.f, 0.f, 0.f};
  f32x4 acc[2][6];
#pragma unroll
  for (int i = 0; i < 2; i++)
#pragma unroll
    for (int j = 0; j < 6; j++) acc[i][j] = zero4;

  const float* stp = srow + (long)(t >> 1) * 256 + (t & 1) * 16;
  ushortt* adst = &As[(t >> 1) * 40 + (t & 1) * 16];

  for (int k0 = 0; k0 < 256; k0 += 32) {
    float4 a0 = *(const float4*)(stp + k0);
    float4 a1 = *(const float4*)(stp + k0 + 4);
    float4 a2 = *(const float4*)(stp + k0 + 8);
    float4 a3 = *(const float4*)(stp + k0 + 12);
    ushortt pk[16];
    pk[0]  = f2b(fexp2(sl * (a0.x - m)) * rinv);
    pk[1]  = f2b(fexp2(sl * (a0.y - m)) * rinv);
    pk[2]  = f2b(fexp2(sl * (a0.z - m)) * rinv);
    pk[3]  = f2b(fexp2(sl * (a0.w - m)) * rinv);
    pk[4]  = f2b(fexp2(sl * (a1.x - m)) * rinv);
    pk[5]  = f2b(fexp2(sl * (a1.y - m)) * rinv);
    pk[6]  = f2b(fexp2(sl * (a1.z - m)) * rinv);
    pk[7]  = f2b(fexp2(sl * (a1.w - m)) * rinv);
    pk[8]  = f2b(fexp2(sl * (a2.x - m)) * rinv);
    pk[9]  = f2b(fexp2(sl * (a2.y - m)) * rinv);
    pk[10] = f2b(fexp2(sl * (a2.z - m)) * rinv);
    pk[11] = f2b(fexp2(sl * (a2.w - m)) * rinv);
    pk[12] = f2b(fexp2(sl * (a3.x - m)) * rinv);
    pk[13] = f2b(fexp2(sl * (a3.y - m)) * rinv);
    pk[14] = f2b(fexp2(sl * (a3.z - m)) * rinv);
    pk[15] = f2b(fexp2(sl * (a3.w - m)) * rinv);
    *(uint4*)adst = *(uint4*)&pk[0];
    *(uint4*)(adst + 8) = *(uint4*)&pk[8];
    __syncthreads();
    bf16x8 af[2], bfr[6];
#pragma unroll
    for (int i = 0; i < 2; i++)
      af[i] = *(const bf16x8*)&As[(w * 32 + i * 16 + lm) * 40 + lg * 8];
#pragma unroll
    for (int j = 0; j < 6; j++)
      bfr[j] = *(const bf16x8*)&Vs[(j * 16 + lm) * 264 + k0 + lg * 8];
#pragma unroll
    for (int i = 0; i < 2; i++)
#pragma unroll
      for (int j = 0; j < 6; j++)
        acc[i][j] = __builtin_amdgcn_mfma_f32_16x16x32_bf16(af[i], bfr[j], acc[i][j], 0, 0, 0);
    __syncthreads();
  }

  int b = z >> 3, h = z & 7;
#pragma unroll
  for (int i = 0; i < 2; i++) {
#pragma unroll
    for (int j = 0; j < 6; j++) {
      int tok = half * 128 + w * 32 + i * 16 + lg * 4;
      int col = j * 16 + lm;
#pragma unroll
      for (int rr2 = 0; rr2 < 4; rr2++) {
        ctxa[((long)(b * 256 + tok + rr2)) * 768 + h * 96 + col] = f2b(acc[i][j][rr2]);
      }
    }
  }
}

// ---------------------------------------------------------------------------
// fp32 GEMM (k2 only now).
// ---------------------------------------------------------------------------
__global__ __launch_bounds__(256) void mk_gemm(
    const float* __restrict__ A, const float* __restrict__ B,
    const float* __restrict__ bias, float* __restrict__ C,
    int M, int N, int K, int lda, int ldb, int ldc, int tilesN)
{
  int tile = blockIdx.x;
  int tm = tile / tilesN, tn = tile - tm * tilesN;
  int m0 = tm << 6, n0 = tn << 6;

  __shared__ float As[16][68];
  __shared__ float Bs[16][68];

  int tid = threadIdx.x;
  int tx = tid & 15, ty = tid >> 4;
  int lrow = tid >> 2;
  int lk = (tid & 3) << 2;

  float acc[4][4];
#pragma unroll
  for (int i = 0; i < 4; i++)
#pragma unroll
    for (int j = 0; j < 4; j++) acc[i][j] = 0.f;

  for (int k0 = 0; k0 < K; k0 += 16) {
    {
      int gm = m0 + lrow;
      float4 v = {0.f, 0.f, 0.f, 0.f};
      if (gm < M) v = *(const float4*)(A + (long)gm * lda + (k0 + lk));
      As[lk + 0][lrow] = v.x; As[lk + 1][lrow] = v.y;
      As[lk + 2][lrow] = v.z; As[lk + 3][lrow] = v.w;
    }
    {
      int gn = n0 + lrow;
      float4 v = {0.f, 0.f, 0.f, 0.f};
      if (gn < N) v = *(const float4*)(B + (long)gn * ldb + (k0 + lk));
      Bs[lk + 0][lrow] = v.x; Bs[lk + 1][lrow] = v.y;
      Bs[lk + 2][lrow] = v.z; Bs[lk + 3][lrow] = v.w;
    }
    __syncthreads();
#pragma unroll
    for (int kk = 0; kk < 16; kk++) {
      float4 a = *(const float4*)&As[kk][ty << 2];
      float4 b = *(const float4*)&Bs[kk][tx << 2];
      acc[0][0] += a.x * b.x; acc[0][1] += a.x * b.y; acc[0][2] += a.x * b.z; acc[0][3] += a.x * b.w;
      acc[1][0] += a.y * b.x; acc[1][1] += a.y * b.y; acc[1][2] += a.y * b.z; acc[1][3] += a.y * b.w;
      acc[2][0] += a.z * b.x; acc[2][1] += a.z * b.y; acc[2][2] += a.z * b.z; acc[2][3] += a.z * b.w;
      acc[3][0] += a.w * b.x; acc[3][1] += a.w * b.y; acc[3][2] += a.w * b.z; acc[3][3] += a.w * b.w;
    }
    __syncthreads();
  }

#pragma unroll
  for (int i = 0; i < 4; i++) {
    int gm = m0 + (ty << 2) + i;
    if (gm >= M) continue;
#pragma unroll
    for (int j = 0; j < 4; j++) {
      int gn = n0 + (tx << 2) + j;
      if (gn >= N) continue;
      float v = acc[i][j];
      if (bias) v += bias[gn];
      C[(long)gm * ldc + gn] = v;
    }
  }
}

// ---------------------------------------------------------------------------
__global__ __launch_bounds__(256) void mk_gates(const float* __restrict__ q2,
                                                const float* __restrict__ k2,
                                                float* __restrict__ gacc)
{
  __shared__ float k2p[8 * 808];
  int b = blockIdx.x >> 4, q = blockIdx.x & 15;
  for (int i = threadIdx.x; i < 6144; i += 256) {
    int e = i / 768, rem = i - e * 768;
    int h = rem / 96, j = rem - h * 96;
    k2p[e * 808 + h * 100 + j] = k2[i];
  }
  __syncthreads();
  const float scale = 0.10206207261596577f;
  int wid = threadIdx.x >> 6, lane = threadIdx.x & 63;
  int h = lane >> 3, e = lane & 7;
  const float* kp = &k2p[e * 808 + h * 100];
  float accL = 0.f;
#pragma unroll
  for (int ti = 0; ti < 4; ti++) {
    int l = q * 16 + wid * 4 + ti;
    const float* qh = q2 + ((long)b * LTOK + l) * DIMC + h * 96;
    float sum = 0.f;
#pragma unroll
    for (int j = 0; j < 96; j += 4) {
      float4 qv = *(const float4*)(qh + j);
      float4 kv = *(const float4*)(kp + j);
      sum += qv.x * kv.x + qv.y * kv.y + qv.z * kv.z + qv.w * kv.w;
    }
    float s = sum * scale;
    float mx = s;
#pragma unroll
    for (int o = 1; o <= 4; o <<= 1) mx = fmaxf(mx, __shfl_xor(mx, o, 64));
    float ex = fexp2((s - mx) * LOG2E);
    float se = ex;
#pragma unroll
    for (int o = 1; o <= 4; o <<= 1) se += __shfl_xor(se, o, 64);
    accL += ex / se;
  }
#pragma unroll
  for (int o = 8; o <= 32; o <<= 1) accL += __shfl_xor(accL, o, 64);
  __shared__ float red[4][8];
  if (lane < 8) red[wid][lane] = accL;
  __syncthreads();
  if (threadIdx.x < 8) {
    float v = red[0][threadIdx.x] + red[1][threadIdx.x] +
              red[2][threadIdx.x] + red[3][threadIdx.x];
    atomicAdd(&gacc[b * 8 + threadIdx.x], v);
  }
}

__global__ __launch_bounds__(64) void mk_gatetop(const float* __restrict__ gacc,
                                                 int* __restrict__ pe,
                                                 float* __restrict__ pw)
{
  int b = threadIdx.x;
  if (b >= 16) return;
  float g[8];
  for (int e = 0; e < 8; e++) g[e] = gacc[b * 8 + e] * (1.f / (8.f * 256.f));
  float mx = g[0];
  for (int e = 1; e < 8; e++) mx = fmaxf(mx, g[e]);
  float se = 0.f;
  for (int e = 0; e < 8; e++) { g[e] = expf(g[e] - mx); se += g[e]; }
  for (int e = 0; e < 8; e++) g[e] /= se;
  int i0 = 0;
  for (int e = 1; e < 8; e++) if (g[e] > g[i0]) i0 = e;
  int i1 = (i0 == 0) ? 1 : 0;
  for (int e = 0; e < 8; e++) if (e != i0 && g[e] > g[i1]) i1 = e;
  float w0 = 1.f / (1.f + expf(g[i1] - g[i0]));
  pe[2 * b] = i0; pe[2 * b + 1] = i1;
  pw[2 * b] = w0; pw[2 * b + 1] = 1.f - w0;
}

// ---------------------------------------------------------------------------
// Depthwise conv + SiLU: 8 tokens/block, weights hoisted to registers.
// grid 1024 = 32 p x 32 token-groups.
// ---------------------------------------------------------------------------
__global__ __launch_bounds__(768) void mk_conv(const float* __restrict__ xzx,
                                               const float* __restrict__ cw,
                                               const float* __restrict__ cb,
                                               const int* __restrict__ pe,
                                               float* __restrict__ xc)
{
  int blk = blockIdx.x;
  int p = blk >> 5, tg = blk & 31;
  int e = pe[p];
  int c = threadIdx.x;
  const float* wp = cw + ((long)e * DIMC + c) * 9;
  float w9[9];
#pragma unroll
  for (int i = 0; i < 9; i++) w9[i] = wp[i];
  float bias = cb[e * DIMC + c];
  const float* xb = xzx + (long)p * LTOK * DIMC + c;
#pragma unroll
  for (int i = 0; i < 8; i++) {
    int t = tg * 8 + i;
    int h = t >> 4, w = t & 15;
    float acc = bias;
#pragma unroll
    for (int dh = 0; dh < 3; dh++) {
      int hh = h + dh - 1;
      if (hh < 0 || hh > 15) continue;
#pragma unroll
      for (int dw = 0; dw < 3; dw++) {
        int ww = w + dw - 1;
        if (ww < 0 || ww > 15) continue;
        acc += xb[(long)(hh * 16 + ww) * DIMC] * w9[dh * 3 + dw];
      }
    }
    xc[((long)p * LTOK + t) * DIMC + c] = acc / (1.f + fexp2(-acc * LOG2E));
  }
}

__device__ __forceinline__ int tmap(int dir, int s) {
  if (dir == 0) return s;
  if (dir == 1) return 255 - s;
  if (dir == 2) return ((s & 15) << 4) | (s >> 4);
  int u = 255 - s;
  return ((u & 15) << 4) | (u >> 4);
}

// ---------------------------------------------------------------------------
// dbl: wave-per-token, lanes on channel dim. Output dblm2[p] per-dir
// traversal order, bank-staggered ss=(s&31)*8+(s>>5). Also zeros eo
// (blocks 0..95) replacing a memset dispatch.
// ---------------------------------------------------------------------------
__global__ __launch_bounds__(256) void mk_dbl(const float* __restrict__ xc,
                                              const float* __restrict__ xproj,
                                              const int* __restrict__ pe,
                                              float* __restrict__ dblm,
                                              float* __restrict__ eo)
{
  if (blockIdx.x < 96) eo[blockIdx.x * 256 + threadIdx.x] = 0.f;
  int p = blockIdx.x >> 6;
  int tq = blockIdx.x & 63;
  int wid = threadIdx.x >> 6, lane = threadIdx.x & 63;
  int m = tq * 4 + wid;
  int e = pe[p];
  const float* xr = xc + ((long)p * LTOK + m) * DIMC;
  const float* wb = xproj + (long)e * 24 * DIMC;
  float4 xv[3];
#pragma unroll
  for (int j = 0; j < 3; j++) xv[j] = *(const float4*)(xr + j * 256 + lane * 4);
  float acc[24];
#pragma unroll
  for (int r = 0; r < 24; r++) {
    const float* wr = wb + r * DIMC;
    float s = 0.f;
#pragma unroll
    for (int j = 0; j < 3; j++) {
      float4 wv = *(const float4*)(wr + j * 256 + lane * 4);
      s += xv[j].x * wv.x + xv[j].y * wv.y + xv[j].z * wv.z + xv[j].w * wv.w;
    }
    acc[r] = s;
  }
#pragma unroll
  for (int r = 0; r < 24; r++)
#pragma unroll
    for (int o = 32; o; o >>= 1) acc[r] += __shfl_xor(acc[r], o, 64);
  if (lane == 0) {
    float* o = dblm + (long)p * 6144;
#pragma unroll
    for (int dd = 0; dd < 4; dd++) {
      int s = tmap(dd, m);
      int ss = ((s & 31) << 3) | (s >> 5);
      float* oa = o + dd * 1024 + ss * 4;
      oa[0] = acc[dd * 6 + 0]; oa[1] = acc[dd * 6 + 1];
      oa[2] = acc[dd * 6 + 2]; oa[3] = acc[dd * 6 + 3];
      float* ob = o + 4096 + dd * 512 + ss * 2;
      ob[0] = acc[dd * 6 + 4]; ob[1] = acc[dd * 6 + 5];
    }
  }
}

// ---------------------------------------------------------------------------
// Fused segmented scan (r7 state: 155us structural floor, kept as control).
// ---------------------------------------------------------------------------
__global__ __launch_bounds__(512, 6) void mk_scan(const float* __restrict__ xc,
                                               const float* __restrict__ dblm,
                                               const float* __restrict__ dtw,
                                               const float* __restrict__ dtb,
                                               const float* __restrict__ Alog,
                                               const float* __restrict__ Dp,
                                               const int* __restrict__ pe,
                                               float* __restrict__ yac)
{
  __shared__ __attribute__((aligned(16))) float dtS[4096];   // [dir][ss][4]
  __shared__ __attribute__((aligned(16))) float bcS[2048];   // [dir][ss][2]
  __shared__ float yS[256 * 18];
  __shared__ float ahS[32][16][2];
  __shared__ float dsum[16];
  int blk = blockIdx.x;
  int p = blk / 48, cg = blk - p * 48;
  int c0 = cg << 4;
  int e = pe[p];
  int tid = threadIdx.x;
  {
    const float4* src = (const float4*)(dblm + (long)p * 6144);
    float4* dA = (float4*)dtS;
    for (int i = tid; i < 1024; i += 512) dA[i] = src[i];
    if (tid < 512) ((float4*)bcS)[tid] = src[1024 + tid];
  }
  for (int i = tid; i < 256 * 18; i += 512) yS[i] = 0.f;
  if (tid < 16) {
    float s = 0.f;
#pragma unroll
    for (int dd = 0; dd < 4; dd++) s += Dp[(long)(e * 4 + dd) * DIMC + c0 + tid];
    dsum[tid] = s;
  }
  __syncthreads();

  int c = tid & 15;
  int rr = tid >> 4;
  int seg = rr & 7;
  int dir = rr >> 3;
  int d = c0 + c;
  const float* xcp = xc + (long)p * LTOK * DIMC + d;
  long pb = (long)(e * 4 + dir) * DIMC + d;
  float4 wv = *(const float4*)(dtw + pb * 4);
  wv.x *= LOG2E; wv.y *= LOG2E; wv.z *= LOG2E; wv.w *= LOG2E;
  float bdt = dtb[pb] * LOG2E;
  float Ad = -fexp2(Alog[pb] * LOG2E);
  int t0 = seg << 5;
  const float* dtP = &dtS[(dir << 10) + (seg << 2)];
  const float* bcP = &bcS[(dir << 9) + (seg << 1)];

  float h = 0.f, ap = 1.f;
#pragma unroll 1
  for (int tb = 0; tb < 32; tb += 4) {
#pragma unroll
    for (int u = 0; u < 4; u++) {
      int i = tb + u;
      float4 dv = *(const float4*)(dtP + i * 32);
      float2 bc = *(const float2*)(bcP + i * 16);
      int mm = tmap(dir, t0 + i);
      float xv = xcp[(long)mm * DIMC];
      float xl = wv.x * dv.x + wv.y * dv.y + wv.z * dv.z + wv.w * dv.w + bdt;
      float te = fexp2(xl);
      float g = flog2(1.f + te);
      g = (xl > 86.f) ? xl : g;
      float de = fexp2(g * Ad);
      h = de * h + (g * LN2 * bc.x) * xv;
      ap *= de;
    }
    __builtin_amdgcn_sched_barrier(0);
  }
  ahS[rr][c][0] = ap;
  ahS[rr][c][1] = h;
  __syncthreads();

  float hh = 0.f;
  {
    int base = dir << 3;
    float av[8], hv[8];
#pragma unroll
    for (int j = 0; j < 8; j++) {
      av[j] = ahS[base + j][c][0];
      hv[j] = ahS[base + j][c][1];
    }
#pragma unroll
    for (int j = 0; j < 7; j++)
      if (j < seg) hh = av[j] * hh + hv[j];
  }

#pragma unroll 1
  for (int tb = 0; tb < 32; tb += 4) {
#pragma unroll
    for (int u = 0; u < 4; u++) {
      int i = tb + u;
      float4 dv = *(const float4*)(dtP + i * 32);
      float2 bc = *(const float2*)(bcP + i * 16);
      int mm = tmap(dir, t0 + i);
      float xv = xcp[(long)mm * DIMC];
      float xl = wv.x * dv.x + wv.y * dv.y + wv.z * dv.z + wv.w * dv.w + bdt;
      float te = fexp2(xl);
      float g = flog2(1.f + te);
      g = (xl > 86.f) ? xl : g;
      float de = fexp2(g * Ad);
      hh = de * hh + (g * LN2 * bc.x) * xv;
      atomicAdd(&yS[mm * 18 + c + (((mm >> 5) & 1) << 1)], hh * bc.y);
    }
    __builtin_amdgcn_sched_barrier(0);
  }
  __syncthreads();

  const float* xcb = xc + (long)p * LTOK * DIMC + c0;
  float* yp = yac + (long)p * LTOK * DIMC + c0;
  for (int i = tid; i < 4096; i += 512) {
    int t = i >> 4, cz = i & 15;
    yp[(long)t * DIMC + cz] = yS[t * 18 + cz + (((t >> 5) & 1) << 1)] +
        xcb[(long)t * DIMC + cz] * dsum[cz];
  }
}

// ---------------------------------------------------------------------------
// LN + silu(z) + token partial-mean. 512 blocks = (p, 16-token slice).
// ---------------------------------------------------------------------------
__global__ __launch_bounds__(256) void mk_lnfin(const float* __restrict__ yac,
                                                const float* __restrict__ xzz,
                                                const float* __restrict__ lns,
                                                const float* __restrict__ lnb,
                                                const int* __restrict__ pe,
                                                float* __restrict__ eo)
{
  int blk = blockIdx.x;
  int p = blk >> 4, ts = blk & 15;
  int e = pe[p];
  int tid = threadIdx.x;
  int wid = tid >> 6, lane = tid & 63;
  float ls[12], lb[12], acc[12];
#pragma unroll
  for (int i = 0; i < 12; i++) {
    int d = i * 64 + lane;
    ls[i] = lns[e * DIMC + d];
    lb[i] = lnb[e * DIMC + d];
    acc[i] = 0.f;
  }
#pragma unroll
  for (int tt = 0; tt < 4; tt++) {
    int t = ts * 16 + wid * 4 + tt;
    const float* yr = yac + ((long)p * LTOK + t) * DIMC;
    const float* zr = xzz + ((long)p * LTOK + t) * DIMC;
    float v[12];
    float s = 0.f;
#pragma unroll
    for (int i = 0; i < 12; i++) { v[i] = yr[i * 64 + lane]; s += v[i]; }
#pragma unroll
    for (int o = 32; o; o >>= 1) s += __shfl_xor(s, o, 64);
    float mu = s * (1.f / 768.f);
    float sq = 0.f;
#pragma unroll
    for (int i = 0; i < 12; i++) { float dlt = v[i] - mu; sq += dlt * dlt; }
#pragma unroll
    for (int o = 32; o; o >>= 1) sq += __shfl_xor(sq, o, 64);
    float rs = rsqrtf(sq * (1.f / 768.f) + 1e-5f);
#pragma unroll
    for (int i = 0; i < 12; i++) {
      float y = (v[i] - mu) * rs * ls[i] + lb[i];
      float z = zr[i * 64 + lane];
      y *= z / (1.f + fexp2(-z * LOG2E));
      acc[i] += y;
    }
  }
  __shared__ float sacc[768];
  for (int j = tid; j < 768; j += 256) sacc[j] = 0.f;
  __syncthreads();
#pragma unroll
  for (int i = 0; i < 12; i++) atomicAdd(&sacc[i * 64 + lane], acc[i]);
  __syncthreads();
  for (int j = tid; j < 768; j += 256) atomicAdd(&eo[(long)p * DIMC + j], sacc[j]);
}

__global__ __launch_bounds__(768) void mk_out(const float* __restrict__ eo,
                                              const float* __restrict__ pw,
                                              float* __restrict__ out)
{
  int b = blockIdx.x, d = threadIdx.x;
  float v = pw[2 * b] * eo[(long)(2 * b) * DIMC + d] +
            pw[2 * b + 1] * eo[(long)(2 * b + 1) * DIMC + d];
  out[b * DIMC + d] = v * (1.f / 256.f);
}

// ---------------------------------------------------------------------------
extern "C" void kernel_launch(void* const* d_in, const int* in_sizes, int n_in,
                              void* d_out, int out_size, void* d_ws, size_t ws_size,
                              hipStream_t stream)
{
  const float* x        = (const float*)d_in[0];
  const float* sa_in_w  = (const float*)d_in[1];
  const float* sa_in_b  = (const float*)d_in[2];
  const float* sa_out_w = (const float*)d_in[3];
  const float* sa_out_b = (const float*)d_in[4];
  const float* ca_in_w  = (const float*)d_in[5];
  const float* ca_in_b  = (const float*)d_in[6];
  const float* eq       = (const float*)d_in[7];
  const float* e_in_w   = (const float*)d_in[8];
  const float* e_in_b   = (const float*)d_in[9];
  const float* e_conv_w = (const float*)d_in[10];
  const float* e_conv_b = (const float*)d_in[11];
  const float* e_xproj  = (const float*)d_in[12];
  const float* e_dtw    = (const float*)d_in[13];
  const float* e_dtb    = (const float*)d_in[14];
  const float* e_Alog   = (const float*)d_in[15];
  const float* e_D      = (const float*)d_in[16];
  const float* e_lns    = (const float*)d_in[17];
  const float* e_lnb    = (const float*)d_in[18];
  float* out = (float*)d_out;

  float* ws = (float*)d_ws;
  // ---- attention phase (float offsets) ----
  ushortt* qk_b   = (ushortt*)(ws + 0);          // 4096x1536 bf16  [0 .. 3,145,728)
  float*   scores = ws + 6291456;                // [6,291,456 .. 14,680,064)
  ushortt* ctxa_b = (ushortt*)(ws + 14680064);   // 4096x768 bf16 [.. 16,252,928)
  // (outside scores; dead before mk_cast writes ew_b over this region)
  ushortt* vt_b   = (ushortt*)(ws + 18874368);   // 128x128x256 bf16 [.. 20,971,520)
  ushortt* xb     = (ushortt*)(ws + 20971520);   // [.. 22,544,384)
  ushortt* wqkv_b = (ushortt*)(ws + 22544384);   // [.. 23,429,120)
  ushortt* saow_b = (ushortt*)(ws + 23429120);   // [.. 23,724,032)
  ushortt* caw_b  = (ushortt*)(ws + 23724032);   // [.. 24,018,944)
  ushortt* ctx_b  = (ushortt*)(ws + 0);          // overlay qk_b (dead post-scores)
  float*   q2     = ws + 1572864;                // [.. 4,718,592) (qk_b dead)
  // ---- persistent smalls ----
  float*   k2     = ws + 25165824;
  int*     pe     = (int*)(ws + 25171968);
  float*   pw     = ws + 25172000;
  float*   eo     = ws + 25172032;               // [.. 25,196,608)
  float*   gacc   = ws + 25393216;               // [.. 25,393,344) peak 101.6MB
  // ---- expert phase ----
  float*   xz_x   = ws + 0;                      // [.. 6,291,456)
  float*   xz_z   = ws + 6291456;                // [.. 12,582,912) live -> lnfin
  ushortt* ew_b   = (ushortt*)(ws + 12582912);   // [.. 17,301,504) (scores+ctxa dead)
  float*   xc     = ws + 12582912;               // [.. 18,874,368) after ew_b dead
  float*   yac    = ws + 18874368;               // [.. 25,165,824)
  float*   dblm   = ws + 0;                      // 32x6144 [.. 196,608) xz_x dead post-conv

  // 0. fused upfront casts + gacc zero
  mk_mcast4<<<5952, 256, 0, stream>>>(x, xb, sa_in_w, wqkv_b, sa_out_w, saow_b,
                                      ca_in_w, caw_b, gacc);
  // 1. qkv MFMA: q,k -> qk_b bf16 (ld 1536); v -> vt_b transposed bf16
  mk_mfma<<<dim3(576, 1), 256, 0, stream>>>(xb, wqkv_b, sa_in_b, qk_b,
      768, 768, 768, 1536, 1, 0, 0, 0, 0, 0, 0, 0, nullptr, 18,
      1, 1536, vt_b, 0, 1, 1);
  // 2. scores = q @ k^T  (bf16 MFMA, K=96, Z=128, fp32 out)
  mk_mfma<<<dim3(4, 128), 256, 0, stream>>>(qk_b, qk_b + 768, nullptr, scores,
      96, 1536, 1536, 256, 8, 393216, 96, 393216, 96, 524288, 65536, 0, nullptr, 2,
      0, 1 << 30, nullptr, 0, 0, 0);
  // 3. fused softmax + att@V -> ctxa bf16 (replaces 2 dispatches)
  mk_attv<<<dim3(2, 128), 256, 0, stream>>>(scores, vt_b, ctxa_b);
  // 4. ctx = ctxa @ sa_out_w^T + b -> bf16  (consumes ctxa BEFORE ew cast)
  mk_mfma<<<dim3(192, 1), 256, 0, stream>>>(ctxa_b, saow_b, sa_out_b, ctx_b,
      768, 768, 768, 768, 1, 0, 0, 0, 0, 0, 0, 0, nullptr, 6,
      1, 1 << 30, nullptr, 0, 0, 0);
  // 4b. cast expert weights (scores/ctxa regions now dead)
  mk_cast<<<9216, 256, 0, stream>>>(e_in_w, ew_b, 9437184);
  // 5. q2 = ctx @ ca_in_w[:768]^T + b (fp32 out)
  mk_mfma<<<dim3(192, 1), 256, 0, stream>>>(ctx_b, caw_b, ca_in_b, q2,
      768, 768, 768, 768, 1, 0, 0, 0, 0, 0, 0, 0, nullptr, 6,
      0, 1 << 30, nullptr, 0, 0, 0);
  // 6. k2 = eq @ ca_in_w[768:]^T + b  (8x768x768 fp32)
  mk_gemm<<<dim3(12, 1), 256, 0, stream>>>(eq, ca_in_w + 589824, ca_in_b + 768, k2,
      8, 768, 768, 768, 768, 768, 12);
  // 7. gate (gacc pre-zeroed in mcast4)
  mk_gates<<<256, 256, 0, stream>>>(q2, k2, gacc);
  mk_gatetop<<<1, 64, 0, stream>>>(gacc, pe, pw);
  // 8. xz = x @ e_in_w[e]^T + b (Z=32 pair mode) split -> xz_x | xz_z
  mk_mfma<<<dim3(24, 32), 256, 0, stream>>>(xb, ew_b, e_in_b, xz_x,
      768, 768, 768, 768, 1, 196608, 0, 1179648, 0, 196608, 0, 1536, pe, 12,
      0, 768, xz_z, 768, 0, 0);
  // 9. depthwise conv + SiLU (8 tok/block, hoisted weights)
  mk_conv<<<1024, 768, 0, stream>>>(xz_x, e_conv_w, e_conv_b, pe, xc);
  // 10. dbl projections + eo zero (xz_x region dead)
  mk_dbl<<<2048, 256, 0, stream>>>(xc, e_xproj, pe, dblm, eo);
  // 11. fused segmented scan
  mk_scan<<<1536, 512, 0, stream>>>(xc, dblm, e_dtw, e_dtb, e_Alog, e_D, pe, yac);
  // 12. LN + silu(z) + token mean
  mk_lnfin<<<512, 256, 0, stream>>>(yac, xz_z, e_lns, e_lnb, pe, eo);
  // 13. weighted top-2 combine (1/256 folded)
  mk_out<<<16, 768, 0, stream>>>(eo, pw, out);

  (void)in_sizes; (void)n_in; (void)out_size; (void)ws_size;
}